// Round 1
// baseline (260.145 us; speedup 1.0000x reference)
//
#include <hip/hip_runtime.h>
#include <math.h>

typedef unsigned int  u32;
typedef unsigned short u16;
typedef short bf16x8 __attribute__((ext_vector_type(8)));   // 8 bf16 = 4 VGPRs
typedef float f32x4  __attribute__((ext_vector_type(4)));

// Problem constants (match reference)
#define NN    50000
#define NE    800000
#define ET    (NE + NN)     // edges + self loops = 850000
#define IND   128
#define HIDD  128
#define NH    8
#define OD    64
#define SLOPE 0.2f

// Binned counting sort parameters. Self-loops are NOT staged (round-10
// lesson: sequential self-loop dst overflows per-block LDS buckets; they're
// deterministic, k_place inserts them directly).
#define NB    196           // buckets of 256 nodes: ceil(50000/256)
#define EPB   4096          // edges per binning block
#define NBB   ((NE + EPB - 1) / EPB)   // 196 binning blocks (random edges only)
#define LCAP  64            // LDS cap per (block,bucket): mean 21, +9.4 sigma
#define CAPB  5120          // global cap per bucket: mean 4082, +13 sigma
#define CPAD  16            // counter stride in ints (64 B = own cache line)

// bf16 round-to-nearest-even, returns low 16 bits
__device__ __forceinline__ u32 bf16rne(float f) {
    u32 u = __float_as_uint(f);
    return (u + 0x7fffu + ((u >> 16) & 1u)) >> 16;
}

// leaky_relu(s) == max(s, SLOPE*s) for 0 < SLOPE < 1
#define LR(s) fmaxf((s), SLOPE * (s))

// ---------------------------------------------------------------------------
// Phase 1: LDS-staged radix partition over the NE random edges only.
// ---------------------------------------------------------------------------
__global__ __launch_bounds__(256) void k_bin(
    const int* __restrict__ ei, int* __restrict__ cnt, u32* __restrict__ staging)
{
    __shared__ u32 lbuf[NB * LCAP];   // 50176 B
    __shared__ int lcnt[NB];
    __shared__ int gbase[NB];
    const int t = threadIdx.x;
    const int e0 = blockIdx.x * EPB;

    for (int i = t; i < NB; i += 256) lcnt[i] = 0;
    __syncthreads();

    for (int i = t; i < EPB; i += 256) {
        const int e = e0 + i;
        if (e >= NE) break;
        const int src = ei[e];
        const int dst = ei[NE + e];
        const int b = dst >> 8;
        const int p = atomicAdd(&lcnt[b], 1);       // LDS atomic (cheap)
        lbuf[b * LCAP + p] = ((u32)(dst & 255) << 16) | (u32)src;
    }
    __syncthreads();

    for (int i = t; i < NB; i += 256)
        gbase[i] = atomicAdd(&cnt[i * CPAD], lcnt[i]);
    __syncthreads();

    // flush: thread = bucket; sequential stores -> lines merge in L2
    for (int b = t; b < NB; b += 256) {
        const int n = lcnt[b];
        const int gb = gbase[b];
        u32* dstp = staging + (size_t)b * CAPB + gb;
        const u32* srcp = lbuf + b * LCAP;
        for (int j = 0; j < n; ++j) dstp[j] = srcp[j];
    }
}

// ---------------------------------------------------------------------------
// Phase 2: one block per bucket. Histogram seeded with the self-loop,
// scan, emit rowptr/rowend + self-loop first, place staged u16 src.
// ---------------------------------------------------------------------------
__global__ __launch_bounds__(1024) void k_place(
    const int* __restrict__ cnt, const u32* __restrict__ staging,
    int* __restrict__ rowptr, int* __restrict__ rowend,
    u16* __restrict__ sorted16)
{
    __shared__ int hist[256];
    __shared__ int cur[256];
    __shared__ int scan[256];
    __shared__ int cbase;
    const int b = blockIdx.x;
    const int t = threadIdx.x;
    const int tot = cnt[b * CPAD];

    if (t == 0) {
        int run = 0;
        for (int i = 0; i < b; ++i) run += cnt[i * CPAD] + 256;
        cbase = run;
    }
    if (t < 256) hist[t] = ((b * 256 + t) < NN) ? 1 : 0;   // seed self-loop
    __syncthreads();
    const int base = cbase;

    for (int i = t; i < tot; i += 1024)
        atomicAdd(&hist[staging[(size_t)b * CAPB + i] >> 16], 1);
    __syncthreads();
    if (t < 256) scan[t] = hist[t];
    __syncthreads();
    for (int off = 1; off < 256; off <<= 1) {
        int v = 0;
        if (t < 256 && t >= off) v = scan[t - off];
        __syncthreads();
        if (t < 256) scan[t] += v;
        __syncthreads();
    }
    if (t < 256) {
        const int excl = (t == 0) ? 0 : scan[t - 1];
        const int node = b * 256 + t;
        if (node < NN) {
            rowptr[node] = base + excl;
            rowend[node] = base + excl + hist[t];
            sorted16[base + excl] = (u16)node;   // self-loop first in row
            cur[t] = excl + 1;
        } else {
            cur[t] = excl;
        }
    }
    __syncthreads();
    for (int i = t; i < tot; i += 1024) {
        const u32 v = staging[(size_t)b * CAPB + i];
        const int pos = atomicAdd(&cur[v >> 16], 1);
        sorted16[base + pos] = (u16)(v & 0xffffu);
    }
}

// ---------------------------------------------------------------------------
// Weight prep: transpose W1/W2 to bf16 Wt[j][k] (k contiguous) so MFMA
// B-fragments (8 consecutive k per lane) are 16B chunks. 24576 elems.
// ---------------------------------------------------------------------------
__global__ __launch_bounds__(256) void k_wprep(
    const float* __restrict__ W1, const float* __restrict__ W2,
    u16* __restrict__ Wt1, u16* __restrict__ Wt2)
{
    const int i = blockIdx.x * 256 + threadIdx.x;
    if (i < 128 * 128) {
        const int k = i >> 7, j = i & 127;
        Wt1[j * 128 + k] = (u16)bf16rne(W1[i]);
    } else {
        const int i2 = i - 128 * 128;        // W2: [128][64]
        const int k = i2 >> 6, j = i2 & 63;
        Wt2[j * 128 + k] = (u16)bf16rne(W2[i2]);
    }
}

// ---------------------------------------------------------------------------
// MFMA GEMM1: h1 = x @ W1 (50000x128 @ 128x128), bf16 inputs / fp32 acc.
// Block: 64 rows x 128 cols, 4 waves (wave w = rows 16w..16w+16, 8 col-tiles).
// LDS bf16 tiles with 16B-chunk XOR swizzle -> conflict-free ds_read_b128.
// Layouts (verified): A[m=lane&15][k=quad*8+j]; C/D col=lane&15,row=quad*4+r.
// Epilogue: u16 h1 stores + fused per-head alpha reductions.
// ---------------------------------------------------------------------------
__global__ __launch_bounds__(256) void k_gemm1(
    const float* __restrict__ x, const u16* __restrict__ Wt1,
    const float* __restrict__ a_s, const float* __restrict__ a_d,
    u16* __restrict__ h1s, float* __restrict__ as1, float* __restrict__ ad1)
{
    __shared__ u32 xb[64 * 64];    // 16 KB: 64 rows x 16 chunks x 16B (swizzled)
    __shared__ u32 Wb[128 * 64];   // 32 KB: 128 cols x 16 chunks x 16B (swizzled)
    const int tid = threadIdx.x;
    const int row0 = blockIdx.x * 64;

    {   // stage Wb from Wt1 (bf16 [j][k]): 2048 chunks
        const uint4* Wt = (const uint4*)Wt1;
        for (int p = 0; p < 8; ++p) {
            const int id = p * 256 + tid;
            const int n = id >> 4, c = id & 15;
            *(uint4*)(Wb + n * 64 + ((c ^ (n & 15)) << 2)) = Wt[n * 16 + c];
        }
    }
    // stage xb from x fp32 (convert to bf16): 1024 chunks
    for (int p = 0; p < 4; ++p) {
        const int id = p * 256 + tid;
        const int m = id >> 4, c = id & 15;
        const int row = row0 + m;
        uint4 v = make_uint4(0, 0, 0, 0);
        if (row < NN) {
            const float4 f0 = *(const float4*)(x + (size_t)row * 128 + c * 8);
            const float4 f1 = *(const float4*)(x + (size_t)row * 128 + c * 8 + 4);
            v.x = bf16rne(f0.x) | (bf16rne(f0.y) << 16);
            v.y = bf16rne(f0.z) | (bf16rne(f0.w) << 16);
            v.z = bf16rne(f1.x) | (bf16rne(f1.y) << 16);
            v.w = bf16rne(f1.z) | (bf16rne(f1.w) << 16);
        }
        *(uint4*)(xb + m * 64 + ((c ^ (m & 15)) << 2)) = v;
    }
    __syncthreads();

    const int w = tid >> 6, lane = tid & 63;
    const int nl = lane & 15, quad = lane >> 4;
    f32x4 acc[8] = {};
    for (int kk = 0; kk < 4; ++kk) {
        const int cm = kk * 4 + quad;
        const bf16x8 a = *(const bf16x8*)(xb + (16 * w + nl) * 64 + ((cm ^ nl) << 2));
#pragma unroll
        for (int tn = 0; tn < 8; ++tn) {
            const bf16x8 b = *(const bf16x8*)(Wb + (16 * tn + nl) * 64 + ((cm ^ nl) << 2));
            acc[tn] = __builtin_amdgcn_mfma_f32_16x16x32_bf16(a, b, acc[tn], 0, 0, 0);
        }
    }

#pragma unroll
    for (int tn = 0; tn < 8; ++tn) {
        const float aw = a_s[16 * tn + nl];
        const float dw = a_d[16 * tn + nl];
#pragma unroll
        for (int r = 0; r < 4; ++r) {
            const int row = row0 + 16 * w + quad * 4 + r;   // uniform in 16-lane group
            if (row < NN) {
                const float v = acc[tn][r];
                h1s[(size_t)row * 128 + 16 * tn + nl] = (u16)bf16rne(v);
                float ps = v * aw, pd = v * dw;
                ps += __shfl_xor(ps, 1); ps += __shfl_xor(ps, 2);
                ps += __shfl_xor(ps, 4); ps += __shfl_xor(ps, 8);
                pd += __shfl_xor(pd, 1); pd += __shfl_xor(pd, 2);
                pd += __shfl_xor(pd, 4); pd += __shfl_xor(pd, 8);
                if (nl == 0) {
                    as1[row * NH + tn] = ps;
                    ad1[row * NH + tn] = pd;
                }
            }
        }
    }
}

// ---------------------------------------------------------------------------
// MFMA GEMM2: h2 = act2 @ W2 (50000x128 @ 128x64). act2 already bf16-packed
// (written by k_agg1), staged with chunk swizzle; 4 col-tiles per wave.
// Epilogue: u16 h2 stores + fused single-head alpha reduction (cross-tile
// partials live in the same lane -> in-register sum, then 16-lane shfl).
// ---------------------------------------------------------------------------
__global__ __launch_bounds__(256) void k_gemm2(
    const u32* __restrict__ act2b, const u16* __restrict__ Wt2,
    const float* __restrict__ a_s2, const float* __restrict__ a_d2,
    u16* __restrict__ h2s, float* __restrict__ as2, float* __restrict__ ad2)
{
    __shared__ u32 xb[64 * 64];   // 16 KB
    __shared__ u32 Wb[64 * 64];   // 16 KB
    const int tid = threadIdx.x;
    const int row0 = blockIdx.x * 64;

    {   // stage Wb from Wt2 (bf16 [j<64][k<128]): 1024 chunks
        const uint4* Wt = (const uint4*)Wt2;
        for (int p = 0; p < 4; ++p) {
            const int id = p * 256 + tid;
            const int n = id >> 4, c = id & 15;
            *(uint4*)(Wb + n * 64 + ((c ^ (n & 15)) << 2)) = Wt[n * 16 + c];
        }
    }
    // stage xb from act2b (already bf16 row-major, 16 chunks/row)
    for (int p = 0; p < 4; ++p) {
        const int id = p * 256 + tid;
        const int m = id >> 4, c = id & 15;
        const int row = row0 + m;
        uint4 v = make_uint4(0, 0, 0, 0);
        if (row < NN) v = ((const uint4*)act2b)[(size_t)row * 16 + c];
        *(uint4*)(xb + m * 64 + ((c ^ (m & 15)) << 2)) = v;
    }
    __syncthreads();

    const int w = tid >> 6, lane = tid & 63;
    const int nl = lane & 15, quad = lane >> 4;
    f32x4 acc[4] = {};
    for (int kk = 0; kk < 4; ++kk) {
        const int cm = kk * 4 + quad;
        const bf16x8 a = *(const bf16x8*)(xb + (16 * w + nl) * 64 + ((cm ^ nl) << 2));
#pragma unroll
        for (int tn = 0; tn < 4; ++tn) {
            const bf16x8 b = *(const bf16x8*)(Wb + (16 * tn + nl) * 64 + ((cm ^ nl) << 2));
            acc[tn] = __builtin_amdgcn_mfma_f32_16x16x32_bf16(a, b, acc[tn], 0, 0, 0);
        }
    }

    float aw[4], dw[4];
#pragma unroll
    for (int tn = 0; tn < 4; ++tn) {
        aw[tn] = a_s2[16 * tn + nl];
        dw[tn] = a_d2[16 * tn + nl];
    }
#pragma unroll
    for (int r = 0; r < 4; ++r) {
        const int row = row0 + 16 * w + quad * 4 + r;   // uniform in 16-lane group
        if (row < NN) {
            float ps = 0.f, pd = 0.f;
#pragma unroll
            for (int tn = 0; tn < 4; ++tn) {
                const float v = acc[tn][r];
                h2s[(size_t)row * 64 + 16 * tn + nl] = (u16)bf16rne(v);
                ps += v * aw[tn];
                pd += v * dw[tn];
            }
            ps += __shfl_xor(ps, 1); ps += __shfl_xor(ps, 2);
            ps += __shfl_xor(ps, 4); ps += __shfl_xor(ps, 8);
            pd += __shfl_xor(pd, 1); pd += __shfl_xor(pd, 2);
            pd += __shfl_xor(pd, 4); pd += __shfl_xor(pd, 8);
            if (nl == 0) { as2[row] = ps; ad2[row] = pd; }
        }
    }
}

// ---------------------------------------------------------------------------
// Aggregation layer 1, CSR gather: one node per wave, lane = packed channel
// pair (head = lane>>3). Unroll-4. Fuses /den + ELU; writes act2 as bf16x2.
// ---------------------------------------------------------------------------
__global__ __launch_bounds__(256) void k_agg1(
    const int* __restrict__ rowptr, const int* __restrict__ rowend,
    const u16* __restrict__ sorted16,
    const u32* __restrict__ h1b, const float* __restrict__ as1,
    const float* __restrict__ ad1,
    u32* __restrict__ act2b)
{
    const int node = blockIdx.x * 4 + (threadIdx.x >> 6);
    const int lane = threadIdx.x & 63;
    const int head = lane >> 3;
    const float adh = ad1[node * NH + head];
    const int k0 = rowptr[node], k1 = rowend[node];
    float acc0 = 0.f, acc1 = 0.f, den = 0.f;
    int k = k0;
    for (; k + 4 <= k1; k += 4) {
        const int s0 = sorted16[k],     s1 = sorted16[k + 1];
        const int s2 = sorted16[k + 2], s3 = sorted16[k + 3];
        const u32 u0 = h1b[s0 * 64 + lane];
        const u32 u1 = h1b[s1 * 64 + lane];
        const u32 u2 = h1b[s2 * 64 + lane];
        const u32 u3 = h1b[s3 * 64 + lane];
        const float a0 = as1[s0 * NH + head], a1 = as1[s1 * NH + head];
        const float a2 = as1[s2 * NH + head], a3 = as1[s3 * NH + head];
        const float w0 = __expf(LR(a0 + adh)), w1 = __expf(LR(a1 + adh));
        const float w2 = __expf(LR(a2 + adh)), w3 = __expf(LR(a3 + adh));
        acc0 += w0 * __uint_as_float(u0 << 16);
        acc1 += w0 * __uint_as_float(u0 & 0xffff0000u);
        acc0 += w1 * __uint_as_float(u1 << 16);
        acc1 += w1 * __uint_as_float(u1 & 0xffff0000u);
        acc0 += w2 * __uint_as_float(u2 << 16);
        acc1 += w2 * __uint_as_float(u2 & 0xffff0000u);
        acc0 += w3 * __uint_as_float(u3 << 16);
        acc1 += w3 * __uint_as_float(u3 & 0xffff0000u);
        den  += (w0 + w1) + (w2 + w3);
    }
    for (; k < k1; ++k) {
        const int src = sorted16[k];
        const float w = __expf(LR(as1[src * NH + head] + adh));
        const u32 u = h1b[src * 64 + lane];
        acc0 += w * __uint_as_float(u << 16);
        acc1 += w * __uint_as_float(u & 0xffff0000u);
        den += w;
    }
    const float inv = 1.f / den;                    // self-loop => den > 0
    float v0 = acc0 * inv, v1 = acc1 * inv;
    v0 = v0 > 0.f ? v0 : expm1f(v0);                // ELU
    v1 = v1 > 0.f ? v1 : expm1f(v1);
    act2b[node * 64 + lane] = bf16rne(v0) | (bf16rne(v1) << 16);
}

// ---------------------------------------------------------------------------
// Layer-2 edge weights, node-parallel (dst implicit = node).
// ---------------------------------------------------------------------------
__global__ __launch_bounds__(256) void k_ew2n(
    const int* __restrict__ rowptr, const int* __restrict__ rowend,
    const u16* __restrict__ sorted16,
    const float* __restrict__ as2, const float* __restrict__ ad2,
    float* __restrict__ wbuf2)
{
    const int node = blockIdx.x * 4 + (threadIdx.x >> 6);
    const int lane = threadIdx.x & 63;
    const float adv = ad2[node];
    const int k1 = rowend[node];
    for (int k = rowptr[node] + lane; k < k1; k += 64)
        wbuf2[k] = __expf(LR(as2[(int)sorted16[k]] + adv));
}

// ---------------------------------------------------------------------------
// Aggregation layer 2 + log_softmax: one node per wave, lane = channel (64).
// ---------------------------------------------------------------------------
__global__ __launch_bounds__(256) void k_agg2(
    const int* __restrict__ rowptr, const int* __restrict__ rowend,
    const u16* __restrict__ sorted16, const float* __restrict__ wbuf2,
    const u16* __restrict__ h2s,
    float* __restrict__ out)
{
    const int node = blockIdx.x * 4 + (threadIdx.x >> 6);
    const int lane = threadIdx.x & 63;
    const int k0 = rowptr[node], k1 = rowend[node];
    float acc = 0.f, den = 0.f;
    int k = k0;
    for (; k + 4 <= k1; k += 4) {
        const int s0 = sorted16[k],     s1 = sorted16[k + 1];
        const int s2 = sorted16[k + 2], s3 = sorted16[k + 3];
        const float w0 = wbuf2[k],     w1 = wbuf2[k + 1];
        const float w2 = wbuf2[k + 2], w3 = wbuf2[k + 3];
        const u32 u0 = h2s[s0 * 64 + lane];
        const u32 u1 = h2s[s1 * 64 + lane];
        const u32 u2 = h2s[s2 * 64 + lane];
        const u32 u3 = h2s[s3 * 64 + lane];
        acc += w0 * __uint_as_float(u0 << 16);
        acc += w1 * __uint_as_float(u1 << 16);
        acc += w2 * __uint_as_float(u2 << 16);
        acc += w3 * __uint_as_float(u3 << 16);
        den += (w0 + w1) + (w2 + w3);
    }
    for (; k < k1; ++k) {
        const float w = wbuf2[k];
        acc += w * __uint_as_float((u32)h2s[(int)sorted16[k] * 64 + lane] << 16);
        den += w;
    }
    const float v = acc / den;
    float m = v;
    for (int kk = 1; kk < 64; kk <<= 1) m = fmaxf(m, __shfl_xor(m, kk));
    float se = __expf(v - m);
    for (int kk = 1; kk < 64; kk <<= 1) se += __shfl_xor(se, kk);
    out[node * 64 + lane] = v - m - logf(se);
}

// ---------------------------------------------------------------------------
// Workspace (4-byte units):
//   h1b      [64N] u32 (h1 bf16 row-major) -> reused as h2s [64N] u16
//   as1      [8N]  f32 -> reused as as2 [N]
//   ad1      [8N]  f32 -> reused as ad2 [N]
//   act2b    [64N] u32 (bf16x2 packed)
//   rowptr   [N], rowend [N]
//   sorted16 [ET] u16
//   wbuf2    [ET] f32
//   staging  [NB*CAPB] u32
//   cnt      [NB*CPAD]
//   Wt1      [8192] u32 (bf16 128x128), Wt2 [4096] u32 (bf16 64x128)
// ---------------------------------------------------------------------------
extern "C" void kernel_launch(void* const* d_in, const int* in_sizes, int n_in,
                              void* d_out, int out_size, void* d_ws, size_t ws_size,
                              hipStream_t stream)
{
    (void)in_sizes; (void)n_in; (void)out_size; (void)ws_size;
    const float* x    = (const float*)d_in[0];
    const int*   ei   = (const int*)d_in[1];
    const float* W1   = (const float*)d_in[2];
    const float* as1w = (const float*)d_in[3];
    const float* ad1w = (const float*)d_in[4];
    const float* W2   = (const float*)d_in[6];
    const float* as2w = (const float*)d_in[7];
    const float* ad2w = (const float*)d_in[8];
    float* out = (float*)d_out;

    float* ws = (float*)d_ws;
    u32*   h1b  = (u32*)ws;                           // 64N
    float* as1  = ws + (size_t)64 * NN;               // 8N
    float* ad1  = ws + (size_t)72 * NN;               // 8N
    u32*   act2b = (u32*)(ws + (size_t)80 * NN);      // 64N
    int*   rowptr = (int*)(ws + (size_t)144 * NN);    // N
    int*   rowend = rowptr + NN;                      // N
    u16*   sorted16 = (u16*)(rowend + NN);            // ET u16
    float* wbuf2 = (float*)((u32*)sorted16 + (ET + 1) / 2); // ET f32
    u32*   staging = (u32*)(wbuf2 + ET);              // NB*CAPB
    int*   cnt = (int*)(staging + (size_t)NB * CAPB); // NB*CPAD
    u16*   Wt1 = (u16*)(cnt + NB * CPAD);             // 8192 u32
    u16*   Wt2 = Wt1 + 128 * 128;                     // 4096 u32
    u16*   h1s = (u16*)h1b;
    u16*   h2s = (u16*)h1b;                           // alias (h1 dead after agg1)
    float* as2 = as1;
    float* ad2 = ad1;

    hipMemsetAsync(cnt, 0, NB * CPAD * sizeof(int), stream);

    k_wprep<<<96, 256, 0, stream>>>(W1, W2, Wt1, Wt2);
    k_bin  <<<NBB, 256, 0, stream>>>(ei, cnt, staging);
    k_place<<<NB, 1024, 0, stream>>>(cnt, staging, rowptr, rowend, sorted16);

    k_gemm1<<<782, 256, 0, stream>>>(x, Wt1, as1w, ad1w, h1s, as1, ad1);
    k_agg1 <<<NN / 4, 256, 0, stream>>>(rowptr, rowend, sorted16, h1b, as1, ad1, act2b);
    k_gemm2<<<782, 256, 0, stream>>>(act2b, Wt2, as2w, ad2w, h2s, as2, ad2);
    k_ew2n <<<NN / 4, 256, 0, stream>>>(rowptr, rowend, sorted16, as2, ad2, wbuf2);
    k_agg2 <<<NN / 4, 256, 0, stream>>>(rowptr, rowend, sorted16, wbuf2, h2s, out);
}

// Round 2
// 233.799 us; speedup vs baseline: 1.1127x; 1.1127x over previous
//
#include <hip/hip_runtime.h>
#include <math.h>

typedef unsigned int  u32;
typedef unsigned short u16;
typedef short bf16x8 __attribute__((ext_vector_type(8)));   // 8 bf16 = 4 VGPRs
typedef float f32x4  __attribute__((ext_vector_type(4)));

// Problem constants (match reference)
#define NN    50000
#define NE    800000
#define ET    (NE + NN)     // edges + self loops = 850000
#define IND   128
#define HIDD  128
#define NH    8
#define OD    64
#define SLOPE 0.2f

// Binned counting sort parameters. Self-loops are NOT staged (they're
// deterministic, k_place inserts them directly).
#define NB    196           // buckets of 256 nodes: ceil(50000/256)
#define EPB   4096          // edges per binning block
#define NBB   ((NE + EPB - 1) / EPB)   // 196 binning blocks (random edges only)
#define LCAP  64            // LDS cap per (block,bucket): mean 21, +9.4 sigma
#define CAPB  5120          // global cap per bucket: mean 4082, +13 sigma
#define CPAD  16            // counter stride in ints (64 B = own cache line)

// bf16 round-to-nearest-even, returns low 16 bits
__device__ __forceinline__ u32 bf16rne(float f) {
    u32 u = __float_as_uint(f);
    return (u + 0x7fffu + ((u >> 16) & 1u)) >> 16;
}

// leaky_relu(s) == max(s, SLOPE*s) for 0 < SLOPE < 1
#define LR(s) fmaxf((s), SLOPE * (s))

// ---------------------------------------------------------------------------
// Phase 1: LDS-staged radix partition over the NE random edges only.
// ---------------------------------------------------------------------------
__global__ __launch_bounds__(256) void k_bin(
    const int* __restrict__ ei, int* __restrict__ cnt, u32* __restrict__ staging)
{
    __shared__ u32 lbuf[NB * LCAP];   // 50176 B
    __shared__ int lcnt[NB];
    __shared__ int gbase[NB];
    const int t = threadIdx.x;
    const int e0 = blockIdx.x * EPB;

    for (int i = t; i < NB; i += 256) lcnt[i] = 0;
    __syncthreads();

    for (int i = t; i < EPB; i += 256) {
        const int e = e0 + i;
        if (e >= NE) break;
        const int src = ei[e];
        const int dst = ei[NE + e];
        const int b = dst >> 8;
        const int p = atomicAdd(&lcnt[b], 1);       // LDS atomic (cheap)
        lbuf[b * LCAP + p] = ((u32)(dst & 255) << 16) | (u32)src;
    }
    __syncthreads();

    for (int i = t; i < NB; i += 256)
        gbase[i] = atomicAdd(&cnt[i * CPAD], lcnt[i]);
    __syncthreads();

    // flush: thread = bucket; sequential stores -> lines merge in L2
    for (int b = t; b < NB; b += 256) {
        const int n = lcnt[b];
        const int gb = gbase[b];
        u32* dstp = staging + (size_t)b * CAPB + gb;
        const u32* srcp = lbuf + b * LCAP;
        for (int j = 0; j < n; ++j) dstp[j] = srcp[j];
    }
}

// ---------------------------------------------------------------------------
// Phase 2: one block per bucket. Parallel scan for the bucket base (was a
// serial thread-0 loop over 196 L2-latency loads), histogram seeded with the
// self-loop, scan, emit rowptr/rowend + self-loop first, place staged src.
// ---------------------------------------------------------------------------
__global__ __launch_bounds__(1024) void k_place(
    const int* __restrict__ cnt, const u32* __restrict__ staging,
    int* __restrict__ rowptr, int* __restrict__ rowend,
    u16* __restrict__ sorted16)
{
    __shared__ int hist[256];
    __shared__ int cur[256];
    __shared__ int scan[256];
    __shared__ int cscan[256];
    const int b = blockIdx.x;
    const int t = threadIdx.x;
    const int tot = cnt[b * CPAD];

    if (t < 256) {
        hist[t] = ((b * 256 + t) < NN) ? 1 : 0;   // seed self-loop
        cscan[t] = (t < NB) ? cnt[t * CPAD] : 0;
    }
    __syncthreads();

    // histogram of staged edges (no syncs inside; tot is block-uniform)
    for (int i = t; i < tot; i += 1024)
        atomicAdd(&hist[staging[(size_t)b * CAPB + i] >> 16], 1);

    // parallel inclusive scan of bucket counts -> block base
    for (int off = 1; off < 256; off <<= 1) {
        int v = 0;
        if (t < 256 && t >= off) v = cscan[t - off];
        __syncthreads();
        if (t < 256) cscan[t] += v;
        __syncthreads();
    }
    const int base = (b ? cscan[b - 1] : 0) + (b << 8);

    if (t < 256) scan[t] = hist[t];
    __syncthreads();
    for (int off = 1; off < 256; off <<= 1) {
        int v = 0;
        if (t < 256 && t >= off) v = scan[t - off];
        __syncthreads();
        if (t < 256) scan[t] += v;
        __syncthreads();
    }
    if (t < 256) {
        const int excl = (t == 0) ? 0 : scan[t - 1];
        const int node = b * 256 + t;
        if (node < NN) {
            rowptr[node] = base + excl;
            rowend[node] = base + excl + hist[t];
            sorted16[base + excl] = (u16)node;   // self-loop first in row
            cur[t] = excl + 1;
        } else {
            cur[t] = excl;
        }
    }
    __syncthreads();
    for (int i = t; i < tot; i += 1024) {
        const u32 v = staging[(size_t)b * CAPB + i];
        const int pos = atomicAdd(&cur[v >> 16], 1);
        sorted16[base + pos] = (u16)(v & 0xffffu);
    }
}

// ---------------------------------------------------------------------------
// Weight prep: transpose W1/W2 to bf16 Wt[j][k] (k contiguous) so MFMA
// B-fragments (8 consecutive k per lane) are 16B chunks. Also zeroes cnt
// (replaces the hipMemsetAsync dispatch).
// ---------------------------------------------------------------------------
__global__ __launch_bounds__(256) void k_wprep(
    const float* __restrict__ W1, const float* __restrict__ W2,
    u16* __restrict__ Wt1, u16* __restrict__ Wt2, int* __restrict__ cnt)
{
    const int i = blockIdx.x * 256 + threadIdx.x;
    if (i < NB * CPAD) cnt[i] = 0;
    if (i < 128 * 128) {
        const int k = i >> 7, j = i & 127;
        Wt1[j * 128 + k] = (u16)bf16rne(W1[i]);
    } else {
        const int i2 = i - 128 * 128;        // W2: [128][64]
        const int k = i2 >> 6, j = i2 & 63;
        Wt2[j * 128 + k] = (u16)bf16rne(W2[i2]);
    }
}

// ---------------------------------------------------------------------------
// MFMA GEMM1: h1 = x @ W1 (50000x128 @ 128x128), bf16 inputs / fp32 acc.
// Block: 64 rows x 128 cols, 4 waves (wave w = rows 16w..16w+16, 8 col-tiles).
// LDS bf16 tiles with 16B-chunk XOR swizzle -> conflict-free ds_read_b128.
// Layouts (verified): A[m=lane&15][k=quad*8+j]; C/D col=lane&15,row=quad*4+r.
// Epilogue: u16 h1 stores + fused per-head alpha reductions.
// ---------------------------------------------------------------------------
__global__ __launch_bounds__(256) void k_gemm1(
    const float* __restrict__ x, const u16* __restrict__ Wt1,
    const float* __restrict__ a_s, const float* __restrict__ a_d,
    u16* __restrict__ h1s, float* __restrict__ as1, float* __restrict__ ad1)
{
    __shared__ u32 xb[64 * 64];    // 16 KB: 64 rows x 16 chunks x 16B (swizzled)
    __shared__ u32 Wb[128 * 64];   // 32 KB: 128 cols x 16 chunks x 16B (swizzled)
    const int tid = threadIdx.x;
    const int row0 = blockIdx.x * 64;

    {   // stage Wb from Wt1 (bf16 [j][k]): 2048 chunks
        const uint4* Wt = (const uint4*)Wt1;
        for (int p = 0; p < 8; ++p) {
            const int id = p * 256 + tid;
            const int n = id >> 4, c = id & 15;
            *(uint4*)(Wb + n * 64 + ((c ^ (n & 15)) << 2)) = Wt[n * 16 + c];
        }
    }
    // stage xb from x fp32 (convert to bf16): 1024 chunks
    for (int p = 0; p < 4; ++p) {
        const int id = p * 256 + tid;
        const int m = id >> 4, c = id & 15;
        const int row = row0 + m;
        uint4 v = make_uint4(0, 0, 0, 0);
        if (row < NN) {
            const float4 f0 = *(const float4*)(x + (size_t)row * 128 + c * 8);
            const float4 f1 = *(const float4*)(x + (size_t)row * 128 + c * 8 + 4);
            v.x = bf16rne(f0.x) | (bf16rne(f0.y) << 16);
            v.y = bf16rne(f0.z) | (bf16rne(f0.w) << 16);
            v.z = bf16rne(f1.x) | (bf16rne(f1.y) << 16);
            v.w = bf16rne(f1.z) | (bf16rne(f1.w) << 16);
        }
        *(uint4*)(xb + m * 64 + ((c ^ (m & 15)) << 2)) = v;
    }
    __syncthreads();

    const int w = tid >> 6, lane = tid & 63;
    const int nl = lane & 15, quad = lane >> 4;
    f32x4 acc[8] = {};
    for (int kk = 0; kk < 4; ++kk) {
        const int cm = kk * 4 + quad;
        const bf16x8 a = *(const bf16x8*)(xb + (16 * w + nl) * 64 + ((cm ^ nl) << 2));
#pragma unroll
        for (int tn = 0; tn < 8; ++tn) {
            const bf16x8 b = *(const bf16x8*)(Wb + (16 * tn + nl) * 64 + ((cm ^ nl) << 2));
            acc[tn] = __builtin_amdgcn_mfma_f32_16x16x32_bf16(a, b, acc[tn], 0, 0, 0);
        }
    }

#pragma unroll
    for (int tn = 0; tn < 8; ++tn) {
        const float aw = a_s[16 * tn + nl];
        const float dw = a_d[16 * tn + nl];
#pragma unroll
        for (int r = 0; r < 4; ++r) {
            const int row = row0 + 16 * w + quad * 4 + r;   // uniform in 16-lane group
            if (row < NN) {
                const float v = acc[tn][r];
                h1s[(size_t)row * 128 + 16 * tn + nl] = (u16)bf16rne(v);
                float ps = v * aw, pd = v * dw;
                ps += __shfl_xor(ps, 1); ps += __shfl_xor(ps, 2);
                ps += __shfl_xor(ps, 4); ps += __shfl_xor(ps, 8);
                pd += __shfl_xor(pd, 1); pd += __shfl_xor(pd, 2);
                pd += __shfl_xor(pd, 4); pd += __shfl_xor(pd, 8);
                if (nl == 0) {
                    as1[row * NH + tn] = ps;
                    ad1[row * NH + tn] = pd;
                }
            }
        }
    }
}

// ---------------------------------------------------------------------------
// MFMA GEMM2: h2 = act2 @ W2 (50000x128 @ 128x64). act2 already bf16-packed
// (written by k_agg1), staged with chunk swizzle; 4 col-tiles per wave.
// Epilogue: u16 h2 stores + fused single-head alpha reduction.
// ---------------------------------------------------------------------------
__global__ __launch_bounds__(256) void k_gemm2(
    const u32* __restrict__ act2b, const u16* __restrict__ Wt2,
    const float* __restrict__ a_s2, const float* __restrict__ a_d2,
    u16* __restrict__ h2s, float* __restrict__ as2, float* __restrict__ ad2)
{
    __shared__ u32 xb[64 * 64];   // 16 KB
    __shared__ u32 Wb[64 * 64];   // 16 KB
    const int tid = threadIdx.x;
    const int row0 = blockIdx.x * 64;

    {   // stage Wb from Wt2 (bf16 [j<64][k<128]): 1024 chunks
        const uint4* Wt = (const uint4*)Wt2;
        for (int p = 0; p < 4; ++p) {
            const int id = p * 256 + tid;
            const int n = id >> 4, c = id & 15;
            *(uint4*)(Wb + n * 64 + ((c ^ (n & 15)) << 2)) = Wt[n * 16 + c];
        }
    }
    // stage xb from act2b (already bf16 row-major, 16 chunks/row)
    for (int p = 0; p < 4; ++p) {
        const int id = p * 256 + tid;
        const int m = id >> 4, c = id & 15;
        const int row = row0 + m;
        uint4 v = make_uint4(0, 0, 0, 0);
        if (row < NN) v = ((const uint4*)act2b)[(size_t)row * 16 + c];
        *(uint4*)(xb + m * 64 + ((c ^ (m & 15)) << 2)) = v;
    }
    __syncthreads();

    const int w = tid >> 6, lane = tid & 63;
    const int nl = lane & 15, quad = lane >> 4;
    f32x4 acc[4] = {};
    for (int kk = 0; kk < 4; ++kk) {
        const int cm = kk * 4 + quad;
        const bf16x8 a = *(const bf16x8*)(xb + (16 * w + nl) * 64 + ((cm ^ nl) << 2));
#pragma unroll
        for (int tn = 0; tn < 4; ++tn) {
            const bf16x8 b = *(const bf16x8*)(Wb + (16 * tn + nl) * 64 + ((cm ^ nl) << 2));
            acc[tn] = __builtin_amdgcn_mfma_f32_16x16x32_bf16(a, b, acc[tn], 0, 0, 0);
        }
    }

    float aw[4], dw[4];
#pragma unroll
    for (int tn = 0; tn < 4; ++tn) {
        aw[tn] = a_s2[16 * tn + nl];
        dw[tn] = a_d2[16 * tn + nl];
    }
#pragma unroll
    for (int r = 0; r < 4; ++r) {
        const int row = row0 + 16 * w + quad * 4 + r;   // uniform in 16-lane group
        if (row < NN) {
            float ps = 0.f, pd = 0.f;
#pragma unroll
            for (int tn = 0; tn < 4; ++tn) {
                const float v = acc[tn][r];
                h2s[(size_t)row * 64 + 16 * tn + nl] = (u16)bf16rne(v);
                ps += v * aw[tn];
                pd += v * dw[tn];
            }
            ps += __shfl_xor(ps, 1); ps += __shfl_xor(ps, 2);
            ps += __shfl_xor(ps, 4); ps += __shfl_xor(ps, 8);
            pd += __shfl_xor(pd, 1); pd += __shfl_xor(pd, 2);
            pd += __shfl_xor(pd, 4); pd += __shfl_xor(pd, 8);
            if (nl == 0) { as2[row] = ps; ad2[row] = pd; }
        }
    }
}

// ---------------------------------------------------------------------------
// Aggregation layer 1, CSR gather: one node per wave, lane = packed channel
// pair (accumulation head = lane>>3). 8-edge unroll with lane-split exp:
// each lane computes ONE weight for (edge j = lane>>3, head = lane&7) —
// 8x fewer transcendentals than the per-lane-redundant form — then
// ds_bpermute pulls w(edge j, my head) from lane j*8 + head.
// Fuses /den + ELU; writes act2 as bf16x2.
// ---------------------------------------------------------------------------
__global__ __launch_bounds__(256) void k_agg1(
    const int* __restrict__ rowptr, const int* __restrict__ rowend,
    const u16* __restrict__ sorted16,
    const u32* __restrict__ h1b, const float* __restrict__ as1,
    const float* __restrict__ ad1,
    u32* __restrict__ act2b)
{
    const int node = blockIdx.x * 4 + (threadIdx.x >> 6);
    const int lane = threadIdx.x & 63;
    const int head = lane >> 3;          // accumulation head (channels 16h..)
    const int eh   = lane & 7;           // exp-role head
    const float adh  = ad1[node * NH + head];   // tail-loop dst term
    const float adeh = ad1[node * NH + eh];     // exp-role dst term
    const int k0 = rowptr[node], k1 = rowend[node];
    const int h4 = head << 2;            // bpermute byte addr of my head lane
    float acc0 = 0.f, acc1 = 0.f, den = 0.f;
    int k = k0;
    for (; k + 8 <= k1; k += 8) {
        // one exp per lane: edge j = lane>>3, head = eh
        const int sj = sorted16[k + head];           // head == lane>>3 == my j
        const float wj = __expf(LR(as1[sj * NH + eh] + adeh));
        // all 8 edge srcs (same 16B region, L1-resident)
        int s[8];
#pragma unroll
        for (int j = 0; j < 8; ++j) s[j] = sorted16[k + j];
#pragma unroll
        for (int j = 0; j < 8; ++j) {
            // w(edge j, my head) lives in lane j*8 + head
            const float w = __uint_as_float((u32)
                __builtin_amdgcn_ds_bpermute(h4 + j * 32, (int)__float_as_uint(wj)));
            const u32 u = h1b[s[j] * 64 + lane];
            acc0 += w * __uint_as_float(u << 16);
            acc1 += w * __uint_as_float(u & 0xffff0000u);
            den  += w;
        }
    }
    for (; k < k1; ++k) {
        const int src = sorted16[k];
        const float w = __expf(LR(as1[src * NH + head] + adh));
        const u32 u = h1b[src * 64 + lane];
        acc0 += w * __uint_as_float(u << 16);
        acc1 += w * __uint_as_float(u & 0xffff0000u);
        den += w;
    }
    const float inv = 1.f / den;                    // self-loop => den > 0
    float v0 = acc0 * inv, v1 = acc1 * inv;
    v0 = v0 > 0.f ? v0 : expm1f(v0);                // ELU
    v1 = v1 > 0.f ? v1 : expm1f(v1);
    act2b[node * 64 + lane] = bf16rne(v0) | (bf16rne(v1) << 16);
}

// ---------------------------------------------------------------------------
// Layer-2 edge weights, node-parallel (dst implicit = node).
// ---------------------------------------------------------------------------
__global__ __launch_bounds__(256) void k_ew2n(
    const int* __restrict__ rowptr, const int* __restrict__ rowend,
    const u16* __restrict__ sorted16,
    const float* __restrict__ as2, const float* __restrict__ ad2,
    float* __restrict__ wbuf2)
{
    const int node = blockIdx.x * 4 + (threadIdx.x >> 6);
    const int lane = threadIdx.x & 63;
    const float adv = ad2[node];
    const int k1 = rowend[node];
    for (int k = rowptr[node] + lane; k < k1; k += 64)
        wbuf2[k] = __expf(LR(as2[(int)sorted16[k]] + adv));
}

// ---------------------------------------------------------------------------
// Aggregation layer 2 + log_softmax: one node per wave, lane = channel (64).
// ---------------------------------------------------------------------------
__global__ __launch_bounds__(256) void k_agg2(
    const int* __restrict__ rowptr, const int* __restrict__ rowend,
    const u16* __restrict__ sorted16, const float* __restrict__ wbuf2,
    const u16* __restrict__ h2s,
    float* __restrict__ out)
{
    const int node = blockIdx.x * 4 + (threadIdx.x >> 6);
    const int lane = threadIdx.x & 63;
    const int k0 = rowptr[node], k1 = rowend[node];
    float acc = 0.f, den = 0.f;
    int k = k0;
    for (; k + 4 <= k1; k += 4) {
        const int s0 = sorted16[k],     s1 = sorted16[k + 1];
        const int s2 = sorted16[k + 2], s3 = sorted16[k + 3];
        const float w0 = wbuf2[k],     w1 = wbuf2[k + 1];
        const float w2 = wbuf2[k + 2], w3 = wbuf2[k + 3];
        const u32 u0 = h2s[s0 * 64 + lane];
        const u32 u1 = h2s[s1 * 64 + lane];
        const u32 u2 = h2s[s2 * 64 + lane];
        const u32 u3 = h2s[s3 * 64 + lane];
        acc += w0 * __uint_as_float(u0 << 16);
        acc += w1 * __uint_as_float(u1 << 16);
        acc += w2 * __uint_as_float(u2 << 16);
        acc += w3 * __uint_as_float(u3 << 16);
        den += (w0 + w1) + (w2 + w3);
    }
    for (; k < k1; ++k) {
        const float w = wbuf2[k];
        acc += w * __uint_as_float((u32)h2s[(int)sorted16[k] * 64 + lane] << 16);
        den += w;
    }
    const float v = acc / den;
    float m = v;
    for (int kk = 1; kk < 64; kk <<= 1) m = fmaxf(m, __shfl_xor(m, kk));
    float se = __expf(v - m);
    for (int kk = 1; kk < 64; kk <<= 1) se += __shfl_xor(se, kk);
    out[node * 64 + lane] = v - m - logf(se);
}

// ---------------------------------------------------------------------------
// Workspace (4-byte units):
//   h1b      [64N] u32 (h1 bf16 row-major) -> reused as h2s [64N] u16
//   as1      [8N]  f32 -> reused as as2 [N]
//   ad1      [8N]  f32 -> reused as ad2 [N]
//   act2b    [64N] u32 (bf16x2 packed)
//   rowptr   [N], rowend [N]
//   sorted16 [ET] u16
//   wbuf2    [ET] f32
//   staging  [NB*CAPB] u32
//   cnt      [NB*CPAD]
//   Wt1      [8192] u32 (bf16 128x128), Wt2 [4096] u32 (bf16 64x128)
// ---------------------------------------------------------------------------
extern "C" void kernel_launch(void* const* d_in, const int* in_sizes, int n_in,
                              void* d_out, int out_size, void* d_ws, size_t ws_size,
                              hipStream_t stream)
{
    (void)in_sizes; (void)n_in; (void)out_size; (void)ws_size;
    const float* x    = (const float*)d_in[0];
    const int*   ei   = (const int*)d_in[1];
    const float* W1   = (const float*)d_in[2];
    const float* as1w = (const float*)d_in[3];
    const float* ad1w = (const float*)d_in[4];
    const float* W2   = (const float*)d_in[6];
    const float* as2w = (const float*)d_in[7];
    const float* ad2w = (const float*)d_in[8];
    float* out = (float*)d_out;

    float* ws = (float*)d_ws;
    u32*   h1b  = (u32*)ws;                           // 64N
    float* as1  = ws + (size_t)64 * NN;               // 8N
    float* ad1  = ws + (size_t)72 * NN;               // 8N
    u32*   act2b = (u32*)(ws + (size_t)80 * NN);      // 64N
    int*   rowptr = (int*)(ws + (size_t)144 * NN);    // N
    int*   rowend = rowptr + NN;                      // N
    u16*   sorted16 = (u16*)(rowend + NN);            // ET u16
    float* wbuf2 = (float*)((u32*)sorted16 + (ET + 1) / 2); // ET f32
    u32*   staging = (u32*)(wbuf2 + ET);              // NB*CAPB
    int*   cnt = (int*)(staging + (size_t)NB * CAPB); // NB*CPAD
    u16*   Wt1 = (u16*)(cnt + NB * CPAD);             // 8192 u32
    u16*   Wt2 = Wt1 + 128 * 128;                     // 4096 u32
    u16*   h1s = (u16*)h1b;
    u16*   h2s = (u16*)h1b;                           // alias (h1 dead after agg1)
    float* as2 = as1;
    float* ad2 = ad1;

    k_wprep<<<96, 256, 0, stream>>>(W1, W2, Wt1, Wt2, cnt);
    k_bin  <<<NBB, 256, 0, stream>>>(ei, cnt, staging);
    k_place<<<NB, 1024, 0, stream>>>(cnt, staging, rowptr, rowend, sorted16);

    k_gemm1<<<782, 256, 0, stream>>>(x, Wt1, as1w, ad1w, h1s, as1, ad1);
    k_agg1 <<<NN / 4, 256, 0, stream>>>(rowptr, rowend, sorted16, h1b, as1, ad1, act2b);
    k_gemm2<<<782, 256, 0, stream>>>(act2b, Wt2, as2w, ad2w, h2s, as2, ad2);
    k_ew2n <<<NN / 4, 256, 0, stream>>>(rowptr, rowend, sorted16, as2, ad2, wbuf2);
    k_agg2 <<<NN / 4, 256, 0, stream>>>(rowptr, rowend, sorted16, wbuf2, h2s, out);
}

// Round 3
// 206.675 us; speedup vs baseline: 1.2587x; 1.1312x over previous
//
#include <hip/hip_runtime.h>
#include <math.h>

typedef unsigned int  u32;
typedef unsigned short u16;
typedef short bf16x8 __attribute__((ext_vector_type(8)));   // 8 bf16 = 4 VGPRs
typedef float f32x4  __attribute__((ext_vector_type(4)));

// Problem constants (match reference)
#define NN    50000
#define NE    800000
#define ET    (NE + NN)     // edges + self loops = 850000
#define IND   128
#define HIDD  128
#define NH    8
#define OD    64
#define SLOPE 0.2f

// Binned counting sort parameters. Self-loops are NOT staged (deterministic,
// k_place inserts them directly). Rows are padded to 8-edge groups with a
// NULL node (id NN) whose weight is exactly 0 -> no tail loops, uint4 packs.
#define NB    196           // buckets of 256 nodes: ceil(50000/256)
#define EPB   4096          // edges per binning block
#define NBB   ((NE + EPB - 1) / EPB)   // 196 binning blocks (random edges only)
#define LCAP  64            // LDS cap per (block,bucket): mean 21, +9.4 sigma
#define CAPB  5120          // global cap per bucket: mean 4082, +13 sigma
#define CPAD  16            // counter stride in ints (64 B = own cache line)
#define BSTRIDE 7168        // fixed padded bucket stride (mean ~5248, +26 sigma)

// bf16 round-to-nearest-even, returns low 16 bits
__device__ __forceinline__ u32 bf16rne(float f) {
    u32 u = __float_as_uint(f);
    return (u + 0x7fffu + ((u >> 16) & 1u)) >> 16;
}

// leaky_relu(s) == max(s, SLOPE*s) for 0 < SLOPE < 1
#define LR(s) fmaxf((s), SLOPE * (s))

// ---------------------------------------------------------------------------
// Phase 1: LDS-staged radix partition over the NE random edges only.
// ---------------------------------------------------------------------------
__global__ __launch_bounds__(256) void k_bin(
    const int* __restrict__ ei, int* __restrict__ cnt, u32* __restrict__ staging)
{
    __shared__ u32 lbuf[NB * LCAP];   // 50176 B
    __shared__ int lcnt[NB];
    __shared__ int gbase[NB];
    const int t = threadIdx.x;
    const int e0 = blockIdx.x * EPB;

    for (int i = t; i < NB; i += 256) lcnt[i] = 0;
    __syncthreads();

    for (int i = t; i < EPB; i += 256) {
        const int e = e0 + i;
        if (e >= NE) break;
        const int src = ei[e];
        const int dst = ei[NE + e];
        const int b = dst >> 8;
        const int p = atomicAdd(&lcnt[b], 1);       // LDS atomic (cheap)
        lbuf[b * LCAP + p] = ((u32)(dst & 255) << 16) | (u32)src;
    }
    __syncthreads();

    for (int i = t; i < NB; i += 256)
        gbase[i] = atomicAdd(&cnt[i * CPAD], lcnt[i]);
    __syncthreads();

    // flush: thread = bucket; sequential stores -> lines merge in L2
    for (int b = t; b < NB; b += 256) {
        const int n = lcnt[b];
        const int gb = gbase[b];
        u32* dstp = staging + (size_t)b * CAPB + gb;
        const u32* srcp = lbuf + b * LCAP;
        for (int j = 0; j < n; ++j) dstp[j] = srcp[j];
    }
}

// ---------------------------------------------------------------------------
// Phase 2: one block per bucket, FIXED base b*BSTRIDE (no cross-bucket scan).
// Rows padded to multiples of 8 with null-node entries; self-loop first.
// ---------------------------------------------------------------------------
__global__ __launch_bounds__(1024) void k_place(
    const int* __restrict__ cnt, const u32* __restrict__ staging,
    int* __restrict__ rowptr, int* __restrict__ rowend,
    u16* __restrict__ sorted16)
{
    __shared__ int hist[256];
    __shared__ int cur[256];
    __shared__ int scan[256];
    const int b = blockIdx.x;
    const int t = threadIdx.x;
    const int tot = cnt[b * CPAD];
    const int base = b * BSTRIDE;

    if (t < 256) hist[t] = ((b * 256 + t) < NN) ? 1 : 0;   // seed self-loop
    __syncthreads();

    for (int i = t; i < tot; i += 1024)
        atomicAdd(&hist[staging[(size_t)b * CAPB + i] >> 16], 1);
    __syncthreads();

    if (t < 256) scan[t] = (hist[t] + 7) & ~7;   // padded counts
    __syncthreads();
    for (int off = 1; off < 256; off <<= 1) {
        int v = 0;
        if (t < 256 && t >= off) v = scan[t - off];
        __syncthreads();
        if (t < 256) scan[t] += v;
        __syncthreads();
    }
    if (t < 256) {
        const int padded = (hist[t] + 7) & ~7;
        const int excl = (t == 0) ? 0 : scan[t - 1];
        const int node = b * 256 + t;
        if (node < NN) {
            rowptr[node] = base + excl;
            rowend[node] = base + excl + padded;       // padded end
            sorted16[base + excl] = (u16)node;         // self-loop first
            for (int j = hist[t]; j < padded; ++j)     // null-pad tail
                sorted16[base + excl + j] = (u16)NN;
            cur[t] = excl + 1;
        } else {
            cur[t] = excl;
        }
    }
    __syncthreads();
    for (int i = t; i < tot; i += 1024) {
        const u32 v = staging[(size_t)b * CAPB + i];
        const int pos = atomicAdd(&cur[v >> 16], 1);
        sorted16[base + pos] = (u16)(v & 0xffffu);
    }
}

// ---------------------------------------------------------------------------
// Weight prep: transpose W1/W2 to bf16 Wt[j][k]; zero cnt; init null-node
// entries (h1b row NN = 0, as1 row NN = -1e30, as2[NN] = -1e30).
// ---------------------------------------------------------------------------
__global__ __launch_bounds__(256) void k_wprep(
    const float* __restrict__ W1, const float* __restrict__ W2,
    u16* __restrict__ Wt1, u16* __restrict__ Wt2, int* __restrict__ cnt,
    u32* __restrict__ h1b, float* __restrict__ as1, float* __restrict__ as2)
{
    const int i = blockIdx.x * 256 + threadIdx.x;
    if (i < NB * CPAD) cnt[i] = 0;
    if (i < 64) h1b[(size_t)64 * NN + i] = 0;          // null h1 row (finite)
    if (i < 8)  as1[(size_t)NH * NN + i] = -1e30f;     // null alpha_src L1
    if (i == 8) as2[NN] = -1e30f;                      // null alpha_src L2
    if (i < 128 * 128) {
        const int k = i >> 7, j = i & 127;
        Wt1[j * 128 + k] = (u16)bf16rne(W1[i]);
    } else {
        const int i2 = i - 128 * 128;        // W2: [128][64]
        const int k = i2 >> 6, j = i2 & 63;
        Wt2[j * 128 + k] = (u16)bf16rne(W2[i2]);
    }
}

// ---------------------------------------------------------------------------
// MFMA GEMM1: h1 = x @ W1 (50000x128 @ 128x128), bf16 inputs / fp32 acc.
// ---------------------------------------------------------------------------
__global__ __launch_bounds__(256) void k_gemm1(
    const float* __restrict__ x, const u16* __restrict__ Wt1,
    const float* __restrict__ a_s, const float* __restrict__ a_d,
    u16* __restrict__ h1s, float* __restrict__ as1, float* __restrict__ ad1)
{
    __shared__ u32 xb[64 * 64];    // 16 KB: 64 rows x 16 chunks x 16B (swizzled)
    __shared__ u32 Wb[128 * 64];   // 32 KB
    const int tid = threadIdx.x;
    const int row0 = blockIdx.x * 64;

    {   // stage Wb from Wt1 (bf16 [j][k]): 2048 chunks
        const uint4* Wt = (const uint4*)Wt1;
        for (int p = 0; p < 8; ++p) {
            const int id = p * 256 + tid;
            const int n = id >> 4, c = id & 15;
            *(uint4*)(Wb + n * 64 + ((c ^ (n & 15)) << 2)) = Wt[n * 16 + c];
        }
    }
    for (int p = 0; p < 4; ++p) {
        const int id = p * 256 + tid;
        const int m = id >> 4, c = id & 15;
        const int row = row0 + m;
        uint4 v = make_uint4(0, 0, 0, 0);
        if (row < NN) {
            const float4 f0 = *(const float4*)(x + (size_t)row * 128 + c * 8);
            const float4 f1 = *(const float4*)(x + (size_t)row * 128 + c * 8 + 4);
            v.x = bf16rne(f0.x) | (bf16rne(f0.y) << 16);
            v.y = bf16rne(f0.z) | (bf16rne(f0.w) << 16);
            v.z = bf16rne(f1.x) | (bf16rne(f1.y) << 16);
            v.w = bf16rne(f1.z) | (bf16rne(f1.w) << 16);
        }
        *(uint4*)(xb + m * 64 + ((c ^ (m & 15)) << 2)) = v;
    }
    __syncthreads();

    const int w = tid >> 6, lane = tid & 63;
    const int nl = lane & 15, quad = lane >> 4;
    f32x4 acc[8] = {};
    for (int kk = 0; kk < 4; ++kk) {
        const int cm = kk * 4 + quad;
        const bf16x8 a = *(const bf16x8*)(xb + (16 * w + nl) * 64 + ((cm ^ nl) << 2));
#pragma unroll
        for (int tn = 0; tn < 8; ++tn) {
            const bf16x8 b = *(const bf16x8*)(Wb + (16 * tn + nl) * 64 + ((cm ^ nl) << 2));
            acc[tn] = __builtin_amdgcn_mfma_f32_16x16x32_bf16(a, b, acc[tn], 0, 0, 0);
        }
    }

#pragma unroll
    for (int tn = 0; tn < 8; ++tn) {
        const float aw = a_s[16 * tn + nl];
        const float dw = a_d[16 * tn + nl];
#pragma unroll
        for (int r = 0; r < 4; ++r) {
            const int row = row0 + 16 * w + quad * 4 + r;   // uniform in 16-lane group
            if (row < NN) {
                const float v = acc[tn][r];
                h1s[(size_t)row * 128 + 16 * tn + nl] = (u16)bf16rne(v);
                float ps = v * aw, pd = v * dw;
                ps += __shfl_xor(ps, 1); ps += __shfl_xor(ps, 2);
                ps += __shfl_xor(ps, 4); ps += __shfl_xor(ps, 8);
                pd += __shfl_xor(pd, 1); pd += __shfl_xor(pd, 2);
                pd += __shfl_xor(pd, 4); pd += __shfl_xor(pd, 8);
                if (nl == 0) {
                    as1[row * NH + tn] = ps;
                    ad1[row * NH + tn] = pd;
                }
            }
        }
    }
}

// ---------------------------------------------------------------------------
// MFMA GEMM2: h2 = act2 @ W2 (50000x128 @ 128x64).
// ---------------------------------------------------------------------------
__global__ __launch_bounds__(256) void k_gemm2(
    const u32* __restrict__ act2b, const u16* __restrict__ Wt2,
    const float* __restrict__ a_s2, const float* __restrict__ a_d2,
    u16* __restrict__ h2s, float* __restrict__ as2, float* __restrict__ ad2)
{
    __shared__ u32 xb[64 * 64];   // 16 KB
    __shared__ u32 Wb[64 * 64];   // 16 KB
    const int tid = threadIdx.x;
    const int row0 = blockIdx.x * 64;

    {
        const uint4* Wt = (const uint4*)Wt2;
        for (int p = 0; p < 4; ++p) {
            const int id = p * 256 + tid;
            const int n = id >> 4, c = id & 15;
            *(uint4*)(Wb + n * 64 + ((c ^ (n & 15)) << 2)) = Wt[n * 16 + c];
        }
    }
    for (int p = 0; p < 4; ++p) {
        const int id = p * 256 + tid;
        const int m = id >> 4, c = id & 15;
        const int row = row0 + m;
        uint4 v = make_uint4(0, 0, 0, 0);
        if (row < NN) v = ((const uint4*)act2b)[(size_t)row * 16 + c];
        *(uint4*)(xb + m * 64 + ((c ^ (m & 15)) << 2)) = v;
    }
    __syncthreads();

    const int w = tid >> 6, lane = tid & 63;
    const int nl = lane & 15, quad = lane >> 4;
    f32x4 acc[4] = {};
    for (int kk = 0; kk < 4; ++kk) {
        const int cm = kk * 4 + quad;
        const bf16x8 a = *(const bf16x8*)(xb + (16 * w + nl) * 64 + ((cm ^ nl) << 2));
#pragma unroll
        for (int tn = 0; tn < 4; ++tn) {
            const bf16x8 b = *(const bf16x8*)(Wb + (16 * tn + nl) * 64 + ((cm ^ nl) << 2));
            acc[tn] = __builtin_amdgcn_mfma_f32_16x16x32_bf16(a, b, acc[tn], 0, 0, 0);
        }
    }

    float aw[4], dw[4];
#pragma unroll
    for (int tn = 0; tn < 4; ++tn) {
        aw[tn] = a_s2[16 * tn + nl];
        dw[tn] = a_d2[16 * tn + nl];
    }
#pragma unroll
    for (int r = 0; r < 4; ++r) {
        const int row = row0 + 16 * w + quad * 4 + r;   // uniform in 16-lane group
        if (row < NN) {
            float ps = 0.f, pd = 0.f;
#pragma unroll
            for (int tn = 0; tn < 4; ++tn) {
                const float v = acc[tn][r];
                h2s[(size_t)row * 64 + 16 * tn + nl] = (u16)bf16rne(v);
                ps += v * aw[tn];
                pd += v * dw[tn];
            }
            ps += __shfl_xor(ps, 1); ps += __shfl_xor(ps, 2);
            ps += __shfl_xor(ps, 4); ps += __shfl_xor(ps, 8);
            pd += __shfl_xor(pd, 1); pd += __shfl_xor(pd, 2);
            pd += __shfl_xor(pd, 4); pd += __shfl_xor(pd, 8);
            if (nl == 0) { as2[row] = ps; ad2[row] = pd; }
        }
    }
}

// ---------------------------------------------------------------------------
// Aggregation layer 1: one node per wave. Rows are 8-padded -> every group is
// one uint4 pack (wave-uniform 16B load). Lane-split exp (lane = j*8+h does
// edge j, head h; one exp instr per 8 edges), bpermute to distribute.
// 2-stage software pipeline: 16 row-gathers in flight.
// ---------------------------------------------------------------------------
#define PG1(KK, S, G, WJ) do {                                                \
    const uint4 p = *(const uint4*)(sorted16 + (KK));                         \
    S[0] = p.x & 0xffffu; S[1] = p.x >> 16;                                   \
    S[2] = p.y & 0xffffu; S[3] = p.y >> 16;                                   \
    S[4] = p.z & 0xffffu; S[5] = p.z >> 16;                                   \
    S[6] = p.w & 0xffffu; S[7] = p.w >> 16;                                   \
    const u32 hlf = (head & 4) ? ((head & 2) ? p.w : p.z)                     \
                               : ((head & 2) ? p.y : p.x);                    \
    const u32 sj = (head & 1) ? (hlf >> 16) : (hlf & 0xffffu);                \
    WJ = __expf(LR(as1[sj * NH + eh] + adeh));                                \
    _Pragma("unroll") for (int j = 0; j < 8; ++j)                             \
        G[j] = h1b[S[j] * 64 + lane];                                         \
} while (0)

#define CONS1(G, WJ) do {                                                     \
    _Pragma("unroll") for (int j = 0; j < 8; ++j) {                           \
        const float wv = __uint_as_float((u32)__builtin_amdgcn_ds_bpermute(   \
            h4 + j * 32, (int)__float_as_uint(WJ)));                          \
        acc0 += wv * __uint_as_float(G[j] << 16);                             \
        acc1 += wv * __uint_as_float(G[j] & 0xffff0000u);                     \
        den  += wv; }                                                         \
} while (0)

__global__ __launch_bounds__(256) void k_agg1(
    const int* __restrict__ rowptr, const int* __restrict__ rowend,
    const u16* __restrict__ sorted16,
    const u32* __restrict__ h1b, const float* __restrict__ as1,
    const float* __restrict__ ad1,
    u32* __restrict__ act2b)
{
    const int node = blockIdx.x * 4 + (threadIdx.x >> 6);
    const int lane = threadIdx.x & 63;
    const int head = lane >> 3;          // accumulation head (channels 16h..)
    const int eh   = lane & 7;           // exp-role head
    const float adeh = ad1[node * NH + eh];
    const int k0 = rowptr[node], kend = rowend[node];   // kend-k0 multiple of 8, >=8
    const int h4 = head << 2;
    float acc0 = 0.f, acc1 = 0.f, den = 0.f;
    u32 sA[8], gA[8], sB[8], gB[8];
    float wA, wB;

    PG1(k0, sA, gA, wA);
    int k = k0 + 8;
    while (k + 16 <= kend) {
        PG1(k, sB, gB, wB);      CONS1(gA, wA);
        PG1(k + 8, sA, gA, wA);  CONS1(gB, wB);
        k += 16;
    }
    if (k < kend) {
        PG1(k, sB, gB, wB);  CONS1(gA, wA);  CONS1(gB, wB);
    } else {
        CONS1(gA, wA);
    }

    const float inv = 1.f / den;                    // self-loop => den > 0
    float v0 = acc0 * inv, v1 = acc1 * inv;
    v0 = v0 > 0.f ? v0 : expm1f(v0);                // ELU
    v1 = v1 > 0.f ? v1 : expm1f(v1);
    act2b[node * 64 + lane] = bf16rne(v0) | (bf16rne(v1) << 16);
}

// ---------------------------------------------------------------------------
// Aggregation layer 2 (fused edge weights) + log_softmax. Lane l computes the
// weight for edge (l&7) of the group (one exp instr / 8 edges); bpermute from
// lanes 0..7 broadcasts. Same uint4 packs + 2-stage pipeline.
// ---------------------------------------------------------------------------
#define PG2(KK, S, G, WJ) do {                                                \
    const uint4 p = *(const uint4*)(sorted16 + (KK));                         \
    S[0] = p.x & 0xffffu; S[1] = p.x >> 16;                                   \
    S[2] = p.y & 0xffffu; S[3] = p.y >> 16;                                   \
    S[4] = p.z & 0xffffu; S[5] = p.z >> 16;                                   \
    S[6] = p.w & 0xffffu; S[7] = p.w >> 16;                                   \
    const u32 hlf = (lane & 4) ? ((lane & 2) ? p.w : p.z)                     \
                               : ((lane & 2) ? p.y : p.x);                    \
    const u32 sj = (lane & 1) ? (hlf >> 16) : (hlf & 0xffffu);                \
    WJ = __expf(LR(as2[sj] + adv));                                           \
    _Pragma("unroll") for (int j = 0; j < 8; ++j)                             \
        G[j] = h2s[S[j] * 64 + lane];                                         \
} while (0)

#define CONS2(G, WJ) do {                                                     \
    _Pragma("unroll") for (int j = 0; j < 8; ++j) {                           \
        const float wv = __uint_as_float((u32)__builtin_amdgcn_ds_bpermute(   \
            j << 2, (int)__float_as_uint(WJ)));                               \
        acc += wv * __uint_as_float(((u32)G[j]) << 16);                       \
        den += wv; }                                                          \
} while (0)

__global__ __launch_bounds__(256) void k_agg2(
    const int* __restrict__ rowptr, const int* __restrict__ rowend,
    const u16* __restrict__ sorted16,
    const u16* __restrict__ h2s, const float* __restrict__ as2,
    const float* __restrict__ ad2,
    float* __restrict__ out)
{
    const int node = blockIdx.x * 4 + (threadIdx.x >> 6);
    const int lane = threadIdx.x & 63;
    const float adv = ad2[node];
    const int k0 = rowptr[node], kend = rowend[node];
    float acc = 0.f, den = 0.f;
    u32 sA[8], gA[8], sB[8], gB[8];
    float wA, wB;

    PG2(k0, sA, gA, wA);
    int k = k0 + 8;
    while (k + 16 <= kend) {
        PG2(k, sB, gB, wB);      CONS2(gA, wA);
        PG2(k + 8, sA, gA, wA);  CONS2(gB, wB);
        k += 16;
    }
    if (k < kend) {
        PG2(k, sB, gB, wB);  CONS2(gA, wA);  CONS2(gB, wB);
    } else {
        CONS2(gA, wA);
    }

    const float v = acc / den;
    float m = v;
    for (int kk = 1; kk < 64; kk <<= 1) m = fmaxf(m, __shfl_xor(m, kk));
    float se = __expf(v - m);
    for (int kk = 1; kk < 64; kk <<= 1) se += __shfl_xor(se, kk);
    out[node * 64 + lane] = v - m - logf(se);
}

// ---------------------------------------------------------------------------
// Workspace layout (u32 units, 64B-aligned chunks):
//   h1b [64*(NN+1)] (+null row) -> reused as h2s u16 (null row = stale h1,
//     finite, weight 0)           as1 [8*NN+8] (+null row), ad1 [8*NN]
//   act2b [64*NN], as2 [NN+1] (+null), ad2 [NN]
//   rowptr [NN], rowend [NN] (padded ends)
//   sorted16 [NB*BSTRIDE] u16, staging [NB*CAPB], cnt [NB*CPAD]
//   Wt1 [8192], Wt2 [4096]
// ---------------------------------------------------------------------------
extern "C" void kernel_launch(void* const* d_in, const int* in_sizes, int n_in,
                              void* d_out, int out_size, void* d_ws, size_t ws_size,
                              hipStream_t stream)
{
    (void)in_sizes; (void)n_in; (void)out_size; (void)ws_size;
    const float* x    = (const float*)d_in[0];
    const int*   ei   = (const int*)d_in[1];
    const float* W1   = (const float*)d_in[2];
    const float* as1w = (const float*)d_in[3];
    const float* ad1w = (const float*)d_in[4];
    const float* W2   = (const float*)d_in[6];
    const float* as2w = (const float*)d_in[7];
    const float* ad2w = (const float*)d_in[8];
    float* out = (float*)d_out;

    u32* ws = (u32*)d_ws;
    size_t o = 0;
    auto take = [&](size_t n) { size_t r = o; o += (n + 15) & ~(size_t)15; return r; };

    u32*   h1b      = ws + take((size_t)64 * (NN + 1));
    float* as1      = (float*)(ws + take((size_t)NH * NN + 8));
    float* ad1      = (float*)(ws + take((size_t)NH * NN));
    u32*   act2b    = ws + take((size_t)64 * NN);
    float* as2      = (float*)(ws + take(NN + 1));
    float* ad2      = (float*)(ws + take(NN));
    int*   rowptr   = (int*)(ws + take(NN));
    int*   rowend   = (int*)(ws + take(NN));
    u16*   sorted16 = (u16*)(ws + take(((size_t)NB * BSTRIDE + 1) / 2));
    u32*   staging  = ws + take((size_t)NB * CAPB);
    int*   cnt      = (int*)(ws + take(NB * CPAD));
    u16*   Wt1      = (u16*)(ws + take(8192));
    u16*   Wt2      = (u16*)(ws + take(4096));
    u16*   h1s      = (u16*)h1b;
    u16*   h2s      = (u16*)h1b;          // alias (h1 dead after agg1)

    k_wprep<<<96, 256, 0, stream>>>(W1, W2, Wt1, Wt2, cnt, h1b, as1, as2);
    k_bin  <<<NBB, 256, 0, stream>>>(ei, cnt, staging);
    k_place<<<NB, 1024, 0, stream>>>(cnt, staging, rowptr, rowend, sorted16);

    k_gemm1<<<782, 256, 0, stream>>>(x, Wt1, as1w, ad1w, h1s, as1, ad1);
    k_agg1 <<<NN / 4, 256, 0, stream>>>(rowptr, rowend, sorted16, h1b, as1, ad1, act2b);
    k_gemm2<<<782, 256, 0, stream>>>(act2b, Wt2, as2w, ad2w, h2s, as2, ad2);
    k_agg2 <<<NN / 4, 256, 0, stream>>>(rowptr, rowend, sorted16, h2s, as2, ad2, out);
}

// Round 4
// 193.332 us; speedup vs baseline: 1.3456x; 1.0690x over previous
//
#include <hip/hip_runtime.h>
#include <math.h>

typedef unsigned int  u32;
typedef unsigned short u16;
typedef short bf16x8 __attribute__((ext_vector_type(8)));   // 8 bf16 = 4 VGPRs
typedef float f32x4  __attribute__((ext_vector_type(4)));

// Problem constants (match reference)
#define NN    50000
#define NE    800000
#define ET    (NE + NN)     // edges + self loops = 850000
#define IND   128
#define HIDD  128
#define NH    8
#define OD    64
#define SLOPE 0.2f

// Binned counting sort parameters. Self-loops are NOT staged (deterministic,
// k_place inserts them directly). Rows are padded to 8-edge groups with a
// NULL node (id NN) whose weight is exactly 0 -> no tail loops, uint4 packs.
#define NB    196           // buckets of 256 nodes: ceil(50000/256)
#define EPB   4096          // edges per binning block
#define NBB   ((NE + EPB - 1) / EPB)   // 196 binning blocks (random edges only)
#define LCAP  64            // LDS cap per (block,bucket): mean 21, +9.4 sigma
#define CAPB  5120          // global cap per bucket: mean 4082, +13 sigma
#define CPAD  16            // counter stride in ints (64 B = own cache line)
#define BSTRIDE 7168        // fixed padded bucket stride (mean ~5248, +26 sigma)

// Extended GEMM widths: alpha reductions folded in as extra columns.
// GEMM1: cols 0..127 = W1, 128..135 = W1@a_src per head, 136..143 = W1@a_dst.
// GEMM2: cols 0..63 = W2, 64 = W2@a_src2, 65 = W2@a_dst2, 66..79 = 0.
#define W1EXT 144
#define W2EXT 80

// bf16 round-to-nearest-even, returns low 16 bits
__device__ __forceinline__ u32 bf16rne(float f) {
    u32 u = __float_as_uint(f);
    return (u + 0x7fffu + ((u >> 16) & 1u)) >> 16;
}

// leaky_relu(s) == max(s, SLOPE*s) for 0 < SLOPE < 1
#define LR(s) fmaxf((s), SLOPE * (s))

// ---------------------------------------------------------------------------
// Phase 1: LDS-staged radix partition over the NE random edges only.
// ---------------------------------------------------------------------------
__global__ __launch_bounds__(256) void k_bin(
    const int* __restrict__ ei, int* __restrict__ cnt, u32* __restrict__ staging)
{
    __shared__ u32 lbuf[NB * LCAP];   // 50176 B
    __shared__ int lcnt[NB];
    __shared__ int gbase[NB];
    const int t = threadIdx.x;
    const int e0 = blockIdx.x * EPB;

    for (int i = t; i < NB; i += 256) lcnt[i] = 0;
    __syncthreads();

    for (int i = t; i < EPB; i += 256) {
        const int e = e0 + i;
        if (e >= NE) break;
        const int src = ei[e];
        const int dst = ei[NE + e];
        const int b = dst >> 8;
        const int p = atomicAdd(&lcnt[b], 1);       // LDS atomic (cheap)
        lbuf[b * LCAP + p] = ((u32)(dst & 255) << 16) | (u32)src;
    }
    __syncthreads();

    for (int i = t; i < NB; i += 256)
        gbase[i] = atomicAdd(&cnt[i * CPAD], lcnt[i]);
    __syncthreads();

    // flush: thread = bucket; sequential stores -> lines merge in L2
    for (int b = t; b < NB; b += 256) {
        const int n = lcnt[b];
        const int gb = gbase[b];
        u32* dstp = staging + (size_t)b * CAPB + gb;
        const u32* srcp = lbuf + b * LCAP;
        for (int j = 0; j < n; ++j) dstp[j] = srcp[j];
    }
}

// ---------------------------------------------------------------------------
// Phase 2: one block per bucket, FIXED base b*BSTRIDE (no cross-bucket scan).
// Rows padded to multiples of 8 with null-node entries; self-loop first.
// ---------------------------------------------------------------------------
__global__ __launch_bounds__(1024) void k_place(
    const int* __restrict__ cnt, const u32* __restrict__ staging,
    int* __restrict__ rowptr, int* __restrict__ rowend,
    u16* __restrict__ sorted16)
{
    __shared__ int hist[256];
    __shared__ int cur[256];
    __shared__ int scan[256];
    const int b = blockIdx.x;
    const int t = threadIdx.x;
    const int tot = cnt[b * CPAD];
    const int base = b * BSTRIDE;

    if (t < 256) hist[t] = ((b * 256 + t) < NN) ? 1 : 0;   // seed self-loop
    __syncthreads();

    for (int i = t; i < tot; i += 1024)
        atomicAdd(&hist[staging[(size_t)b * CAPB + i] >> 16], 1);
    __syncthreads();

    if (t < 256) scan[t] = (hist[t] + 7) & ~7;   // padded counts
    __syncthreads();
    for (int off = 1; off < 256; off <<= 1) {
        int v = 0;
        if (t < 256 && t >= off) v = scan[t - off];
        __syncthreads();
        if (t < 256) scan[t] += v;
        __syncthreads();
    }
    if (t < 256) {
        const int padded = (hist[t] + 7) & ~7;
        const int excl = (t == 0) ? 0 : scan[t - 1];
        const int node = b * 256 + t;
        if (node < NN) {
            rowptr[node] = base + excl;
            rowend[node] = base + excl + padded;       // padded end
            sorted16[base + excl] = (u16)node;         // self-loop first
            for (int j = hist[t]; j < padded; ++j)     // null-pad tail
                sorted16[base + excl + j] = (u16)NN;
            cur[t] = excl + 1;
        } else {
            cur[t] = excl;
        }
    }
    __syncthreads();
    for (int i = t; i < tot; i += 1024) {
        const u32 v = staging[(size_t)b * CAPB + i];
        const int pos = atomicAdd(&cur[v >> 16], 1);
        sorted16[base + pos] = (u16)(v & 0xffffu);
    }
}

// ---------------------------------------------------------------------------
// Weight prep: build EXTENDED transposed bf16 weights Wt[j][k] (k contiguous):
//   Wt1 (144x128): j<128 -> W1[k][j]; j=128+h -> sum_c W1[k][16h+c]*a_s1[h][c];
//                  j=136+h -> same with a_d1.
//   Wt2 (80x128):  j<64 -> W2[k][j]; j=64 -> W2@a_s2; j=65 -> W2@a_d2; else 0.
// Also zero cnt and init null-node entries.
// ---------------------------------------------------------------------------
__global__ __launch_bounds__(256) void k_wprep(
    const float* __restrict__ W1, const float* __restrict__ W2,
    const float* __restrict__ as1w, const float* __restrict__ ad1w,
    const float* __restrict__ as2w, const float* __restrict__ ad2w,
    u16* __restrict__ Wt1, u16* __restrict__ Wt2, int* __restrict__ cnt,
    u32* __restrict__ h1b, float* __restrict__ as1, float* __restrict__ as2)
{
    const int i = blockIdx.x * 256 + threadIdx.x;
    if (i < NB * CPAD) cnt[i] = 0;
    if (i < 64) h1b[(size_t)64 * NN + i] = 0;          // null h1 row (finite)
    if (i < 8)  as1[(size_t)NH * NN + i] = -1e30f;     // null alpha_src L1
    if (i == 8) as2[NN] = -1e30f;                      // null alpha_src L2

    if (i < W1EXT * 128) {
        const int j = i >> 7, k = i & 127;
        float v;
        if (j < 128) {
            v = W1[k * 128 + j];
        } else if (j < 136) {
            const int h = j - 128;
            v = 0.f;
            for (int c = 0; c < 16; ++c)
                v += W1[k * 128 + h * 16 + c] * as1w[h * 16 + c];
        } else {
            const int h = j - 136;
            v = 0.f;
            for (int c = 0; c < 16; ++c)
                v += W1[k * 128 + h * 16 + c] * ad1w[h * 16 + c];
        }
        Wt1[j * 128 + k] = (u16)bf16rne(v);
    } else if (i < W1EXT * 128 + W2EXT * 128) {
        const int i2 = i - W1EXT * 128;
        const int j = i2 >> 7, k = i2 & 127;
        float v = 0.f;
        if (j < 64) {
            v = W2[k * 64 + j];
        } else if (j == 64) {
            for (int c = 0; c < 64; ++c) v += W2[k * 64 + c] * as2w[c];
        } else if (j == 65) {
            for (int c = 0; c < 64; ++c) v += W2[k * 64 + c] * ad2w[c];
        }
        Wt2[j * 128 + k] = (u16)bf16rne(v);
    }
}

// ---------------------------------------------------------------------------
// MFMA GEMM1: [h1 | as1 | ad1] = x @ W1ext (50000x128 @ 128x144).
// Block: 64 rows x 144 cols, 4 waves; 9 col-tiles per wave. Epilogue is pure
// predicated stores (alpha columns come straight out of the MFMA acc).
// ---------------------------------------------------------------------------
__global__ __launch_bounds__(256) void k_gemm1(
    const float* __restrict__ x, const u16* __restrict__ Wt1,
    u16* __restrict__ h1s, float* __restrict__ as1, float* __restrict__ ad1)
{
    __shared__ u32 xb[64 * 64];      // 16 KB: 64 rows x 16 chunks x 16B (swizzled)
    __shared__ u32 Wb[W1EXT * 64];   // 36 KB
    const int tid = threadIdx.x;
    const int row0 = blockIdx.x * 64;

    {   // stage Wb from Wt1 (bf16 [j][k]): 2304 chunks, 9 per thread
        const uint4* Wt = (const uint4*)Wt1;
        for (int p = 0; p < 9; ++p) {
            const int id = p * 256 + tid;
            const int n = id >> 4, c = id & 15;
            *(uint4*)(Wb + n * 64 + ((c ^ (n & 15)) << 2)) = Wt[n * 16 + c];
        }
    }
    for (int p = 0; p < 4; ++p) {
        const int id = p * 256 + tid;
        const int m = id >> 4, c = id & 15;
        const int row = row0 + m;
        uint4 v = make_uint4(0, 0, 0, 0);
        if (row < NN) {
            const float4 f0 = *(const float4*)(x + (size_t)row * 128 + c * 8);
            const float4 f1 = *(const float4*)(x + (size_t)row * 128 + c * 8 + 4);
            v.x = bf16rne(f0.x) | (bf16rne(f0.y) << 16);
            v.y = bf16rne(f0.z) | (bf16rne(f0.w) << 16);
            v.z = bf16rne(f1.x) | (bf16rne(f1.y) << 16);
            v.w = bf16rne(f1.z) | (bf16rne(f1.w) << 16);
        }
        *(uint4*)(xb + m * 64 + ((c ^ (m & 15)) << 2)) = v;
    }
    __syncthreads();

    const int w = tid >> 6, lane = tid & 63;
    const int nl = lane & 15, quad = lane >> 4;
    f32x4 acc[9] = {};
    for (int kk = 0; kk < 4; ++kk) {
        const int cm = kk * 4 + quad;
        const bf16x8 a = *(const bf16x8*)(xb + (16 * w + nl) * 64 + ((cm ^ nl) << 2));
#pragma unroll
        for (int tn = 0; tn < 9; ++tn) {
            const bf16x8 b = *(const bf16x8*)(Wb + (16 * tn + nl) * 64 + ((cm ^ nl) << 2));
            acc[tn] = __builtin_amdgcn_mfma_f32_16x16x32_bf16(a, b, acc[tn], 0, 0, 0);
        }
    }

#pragma unroll
    for (int tn = 0; tn < 8; ++tn) {
#pragma unroll
        for (int r = 0; r < 4; ++r) {
            const int row = row0 + 16 * w + quad * 4 + r;   // uniform in 16-lane group
            if (row < NN)
                h1s[(size_t)row * 128 + 16 * tn + nl] = (u16)bf16rne(acc[tn][r]);
        }
    }
#pragma unroll
    for (int r = 0; r < 4; ++r) {   // tile 8: cols 128..143 = [as1 | ad1]
        const int row = row0 + 16 * w + quad * 4 + r;
        if (row < NN) {
            const float v = acc[8][r];
            if (nl < 8) as1[row * NH + nl] = v;
            else        ad1[row * NH + (nl - 8)] = v;
        }
    }
}

// ---------------------------------------------------------------------------
// MFMA GEMM2: [h2 | as2 | ad2] = act2 @ W2ext (50000x128 @ 128x80).
// ---------------------------------------------------------------------------
__global__ __launch_bounds__(256) void k_gemm2(
    const u32* __restrict__ act2b, const u16* __restrict__ Wt2,
    u16* __restrict__ h2s, float* __restrict__ as2, float* __restrict__ ad2)
{
    __shared__ u32 xb[64 * 64];      // 16 KB
    __shared__ u32 Wb[W2EXT * 64];   // 20 KB
    const int tid = threadIdx.x;
    const int row0 = blockIdx.x * 64;

    {   // stage Wb from Wt2: 1280 chunks, 5 per thread
        const uint4* Wt = (const uint4*)Wt2;
        for (int p = 0; p < 5; ++p) {
            const int id = p * 256 + tid;
            const int n = id >> 4, c = id & 15;
            *(uint4*)(Wb + n * 64 + ((c ^ (n & 15)) << 2)) = Wt[n * 16 + c];
        }
    }
    for (int p = 0; p < 4; ++p) {
        const int id = p * 256 + tid;
        const int m = id >> 4, c = id & 15;
        const int row = row0 + m;
        uint4 v = make_uint4(0, 0, 0, 0);
        if (row < NN) v = ((const uint4*)act2b)[(size_t)row * 16 + c];
        *(uint4*)(xb + m * 64 + ((c ^ (m & 15)) << 2)) = v;
    }
    __syncthreads();

    const int w = tid >> 6, lane = tid & 63;
    const int nl = lane & 15, quad = lane >> 4;
    f32x4 acc[5] = {};
    for (int kk = 0; kk < 4; ++kk) {
        const int cm = kk * 4 + quad;
        const bf16x8 a = *(const bf16x8*)(xb + (16 * w + nl) * 64 + ((cm ^ nl) << 2));
#pragma unroll
        for (int tn = 0; tn < 5; ++tn) {
            const bf16x8 b = *(const bf16x8*)(Wb + (16 * tn + nl) * 64 + ((cm ^ nl) << 2));
            acc[tn] = __builtin_amdgcn_mfma_f32_16x16x32_bf16(a, b, acc[tn], 0, 0, 0);
        }
    }

#pragma unroll
    for (int tn = 0; tn < 4; ++tn) {
#pragma unroll
        for (int r = 0; r < 4; ++r) {
            const int row = row0 + 16 * w + quad * 4 + r;   // uniform in 16-lane group
            if (row < NN)
                h2s[(size_t)row * 64 + 16 * tn + nl] = (u16)bf16rne(acc[tn][r]);
        }
    }
#pragma unroll
    for (int r = 0; r < 4; ++r) {   // tile 4: col 64 = as2, col 65 = ad2
        const int row = row0 + 16 * w + quad * 4 + r;
        if (row < NN) {
            const float v = acc[4][r];
            if (nl == 0) as2[row] = v;
            else if (nl == 1) ad2[row] = v;
        }
    }
}

// ---------------------------------------------------------------------------
// Aggregation layer 1: one node per wave. Rows are 8-padded -> every group is
// one uint4 pack (wave-uniform 16B load). Lane-split exp (lane = j*8+h does
// edge j, head h; one exp instr per 8 edges), bpermute to distribute.
// 2-stage software pipeline: 16 row-gathers in flight.
// ---------------------------------------------------------------------------
#define PG1(KK, S, G, WJ) do {                                                \
    const uint4 p = *(const uint4*)(sorted16 + (KK));                         \
    S[0] = p.x & 0xffffu; S[1] = p.x >> 16;                                   \
    S[2] = p.y & 0xffffu; S[3] = p.y >> 16;                                   \
    S[4] = p.z & 0xffffu; S[5] = p.z >> 16;                                   \
    S[6] = p.w & 0xffffu; S[7] = p.w >> 16;                                   \
    const u32 hlf = (head & 4) ? ((head & 2) ? p.w : p.z)                     \
                               : ((head & 2) ? p.y : p.x);                    \
    const u32 sj = (head & 1) ? (hlf >> 16) : (hlf & 0xffffu);                \
    WJ = __expf(LR(as1[sj * NH + eh] + adeh));                                \
    _Pragma("unroll") for (int j = 0; j < 8; ++j)                             \
        G[j] = h1b[S[j] * 64 + lane];                                         \
} while (0)

#define CONS1(G, WJ) do {                                                     \
    _Pragma("unroll") for (int j = 0; j < 8; ++j) {                           \
        const float wv = __uint_as_float((u32)__builtin_amdgcn_ds_bpermute(   \
            h4 + j * 32, (int)__float_as_uint(WJ)));                          \
        acc0 += wv * __uint_as_float(G[j] << 16);                             \
        acc1 += wv * __uint_as_float(G[j] & 0xffff0000u);                     \
        den  += wv; }                                                         \
} while (0)

__global__ __launch_bounds__(256) void k_agg1(
    const int* __restrict__ rowptr, const int* __restrict__ rowend,
    const u16* __restrict__ sorted16,
    const u32* __restrict__ h1b, const float* __restrict__ as1,
    const float* __restrict__ ad1,
    u32* __restrict__ act2b)
{
    const int node = blockIdx.x * 4 + (threadIdx.x >> 6);
    const int lane = threadIdx.x & 63;
    const int head = lane >> 3;          // accumulation head (channels 16h..)
    const int eh   = lane & 7;           // exp-role head
    const float adeh = ad1[node * NH + eh];
    const int k0 = rowptr[node], kend = rowend[node];   // kend-k0 multiple of 8, >=8
    const int h4 = head << 2;
    float acc0 = 0.f, acc1 = 0.f, den = 0.f;
    u32 sA[8], gA[8], sB[8], gB[8];
    float wA, wB;

    PG1(k0, sA, gA, wA);
    int k = k0 + 8;
    while (k + 16 <= kend) {
        PG1(k, sB, gB, wB);      CONS1(gA, wA);
        PG1(k + 8, sA, gA, wA);  CONS1(gB, wB);
        k += 16;
    }
    if (k < kend) {
        PG1(k, sB, gB, wB);  CONS1(gA, wA);  CONS1(gB, wB);
    } else {
        CONS1(gA, wA);
    }

    const float inv = 1.f / den;                    // self-loop => den > 0
    float v0 = acc0 * inv, v1 = acc1 * inv;
    v0 = v0 > 0.f ? v0 : expm1f(v0);                // ELU
    v1 = v1 > 0.f ? v1 : expm1f(v1);
    act2b[node * 64 + lane] = bf16rne(v0) | (bf16rne(v1) << 16);
}

// ---------------------------------------------------------------------------
// Aggregation layer 2 (fused edge weights) + log_softmax. Lane l computes the
// weight for edge (l&7) of the group (one exp instr / 8 edges); bpermute from
// lanes 0..7 broadcasts. Same uint4 packs + 2-stage pipeline.
// ---------------------------------------------------------------------------
#define PG2(KK, S, G, WJ) do {                                                \
    const uint4 p = *(const uint4*)(sorted16 + (KK));                         \
    S[0] = p.x & 0xffffu; S[1] = p.x >> 16;                                   \
    S[2] = p.y & 0xffffu; S[3] = p.y >> 16;                                   \
    S[4] = p.z & 0xffffu; S[5] = p.z >> 16;                                   \
    S[6] = p.w & 0xffffu; S[7] = p.w >> 16;                                   \
    const u32 hlf = (lane & 4) ? ((lane & 2) ? p.w : p.z)                     \
                               : ((lane & 2) ? p.y : p.x);                    \
    const u32 sj = (lane & 1) ? (hlf >> 16) : (hlf & 0xffffu);                \
    WJ = __expf(LR(as2[sj] + adv));                                           \
    _Pragma("unroll") for (int j = 0; j < 8; ++j)                             \
        G[j] = h2s[S[j] * 64 + lane];                                         \
} while (0)

#define CONS2(G, WJ) do {                                                     \
    _Pragma("unroll") for (int j = 0; j < 8; ++j) {                           \
        const float wv = __uint_as_float((u32)__builtin_amdgcn_ds_bpermute(   \
            j << 2, (int)__float_as_uint(WJ)));                               \
        acc += wv * __uint_as_float(((u32)G[j]) << 16);                       \
        den += wv; }                                                          \
} while (0)

__global__ __launch_bounds__(256) void k_agg2(
    const int* __restrict__ rowptr, const int* __restrict__ rowend,
    const u16* __restrict__ sorted16,
    const u16* __restrict__ h2s, const float* __restrict__ as2,
    const float* __restrict__ ad2,
    float* __restrict__ out)
{
    const int node = blockIdx.x * 4 + (threadIdx.x >> 6);
    const int lane = threadIdx.x & 63;
    const float adv = ad2[node];
    const int k0 = rowptr[node], kend = rowend[node];
    float acc = 0.f, den = 0.f;
    u32 sA[8], gA[8], sB[8], gB[8];
    float wA, wB;

    PG2(k0, sA, gA, wA);
    int k = k0 + 8;
    while (k + 16 <= kend) {
        PG2(k, sB, gB, wB);      CONS2(gA, wA);
        PG2(k + 8, sA, gA, wA);  CONS2(gB, wB);
        k += 16;
    }
    if (k < kend) {
        PG2(k, sB, gB, wB);  CONS2(gA, wA);  CONS2(gB, wB);
    } else {
        CONS2(gA, wA);
    }

    const float v = acc / den;
    float m = v;
    for (int kk = 1; kk < 64; kk <<= 1) m = fmaxf(m, __shfl_xor(m, kk));
    float se = __expf(v - m);
    for (int kk = 1; kk < 64; kk <<= 1) se += __shfl_xor(se, kk);
    out[node * 64 + lane] = v - m - logf(se);
}

// ---------------------------------------------------------------------------
// Workspace layout (u32 units, 64B-aligned chunks).
// ---------------------------------------------------------------------------
extern "C" void kernel_launch(void* const* d_in, const int* in_sizes, int n_in,
                              void* d_out, int out_size, void* d_ws, size_t ws_size,
                              hipStream_t stream)
{
    (void)in_sizes; (void)n_in; (void)out_size; (void)ws_size;
    const float* x    = (const float*)d_in[0];
    const int*   ei   = (const int*)d_in[1];
    const float* W1   = (const float*)d_in[2];
    const float* as1w = (const float*)d_in[3];
    const float* ad1w = (const float*)d_in[4];
    const float* W2   = (const float*)d_in[6];
    const float* as2w = (const float*)d_in[7];
    const float* ad2w = (const float*)d_in[8];
    float* out = (float*)d_out;

    u32* ws = (u32*)d_ws;
    size_t o = 0;
    auto take = [&](size_t n) { size_t r = o; o += (n + 15) & ~(size_t)15; return r; };

    u32*   h1b      = ws + take((size_t)64 * (NN + 1));
    float* as1      = (float*)(ws + take((size_t)NH * NN + 8));
    float* ad1      = (float*)(ws + take((size_t)NH * NN));
    u32*   act2b    = ws + take((size_t)64 * NN);
    float* as2      = (float*)(ws + take(NN + 1));
    float* ad2      = (float*)(ws + take(NN));
    int*   rowptr   = (int*)(ws + take(NN));
    int*   rowend   = (int*)(ws + take(NN));
    u16*   sorted16 = (u16*)(ws + take(((size_t)NB * BSTRIDE + 1) / 2));
    u32*   staging  = ws + take((size_t)NB * CAPB);
    int*   cnt      = (int*)(ws + take(NB * CPAD));
    u16*   Wt1      = (u16*)(ws + take((size_t)W1EXT * 128 / 2));
    u16*   Wt2      = (u16*)(ws + take((size_t)W2EXT * 128 / 2));
    u16*   h1s      = (u16*)h1b;
    u16*   h2s      = (u16*)h1b;          // alias (h1 dead after agg1)

    k_wprep<<<112, 256, 0, stream>>>(W1, W2, as1w, ad1w, as2w, ad2w,
                                     Wt1, Wt2, cnt, h1b, as1, as2);
    k_bin  <<<NBB, 256, 0, stream>>>(ei, cnt, staging);
    k_place<<<NB, 1024, 0, stream>>>(cnt, staging, rowptr, rowend, sorted16);

    k_gemm1<<<782, 256, 0, stream>>>(x, Wt1, h1s, as1, ad1);
    k_agg1 <<<NN / 4, 256, 0, stream>>>(rowptr, rowend, sorted16, h1b, as1, ad1, act2b);
    k_gemm2<<<782, 256, 0, stream>>>(act2b, Wt2, h2s, as2, ad2);
    k_agg2 <<<NN / 4, 256, 0, stream>>>(rowptr, rowend, sorted16, h2s, as2, ad2, out);
}

// Round 5
// 191.189 us; speedup vs baseline: 1.3607x; 1.0112x over previous
//
#include <hip/hip_runtime.h>
#include <math.h>

typedef unsigned int  u32;
typedef unsigned short u16;
typedef short bf16x8 __attribute__((ext_vector_type(8)));   // 8 bf16 = 4 VGPRs
typedef float f32x4  __attribute__((ext_vector_type(4)));

// Problem constants (match reference)
#define NN    50000
#define NE    800000
#define ET    (NE + NN)     // edges + self loops = 850000
#define IND   128
#define HIDD  128
#define NH    8
#define OD    64
#define SLOPE 0.2f

// Binned counting sort parameters. Self-loops are NOT staged (deterministic,
// k_place inserts them directly). Rows are padded to 8-edge groups with a
// NULL node (id NN) whose weight is exactly 0 -> no tail loops, uint4 packs.
#define NB    196           // buckets of 256 nodes: ceil(50000/256)
#define EPB   4096          // edges per binning block
#define NBB   ((NE + EPB - 1) / EPB)   // 196 binning blocks (random edges only)
#define LCAP  64            // LDS cap per (block,bucket): mean 21, +9.4 sigma
#define CAPB  5120          // global cap per bucket: mean 4082, +13 sigma
#define CPAD  16            // counter stride in ints (64 B = own cache line)
#define BSTRIDE 7168        // fixed padded bucket stride (mean ~5248, +26 sigma)

// Extended GEMM widths: alpha reductions folded in as extra columns.
// GEMM1: cols 0..127 = W1, 128..135 = W1@a_src per head, 136..143 = W1@a_dst.
// GEMM2: cols 0..63 = W2, 64 = W2@a_src2, 65 = W2@a_dst2, 66..79 = 0.
#define W1EXT 144
#define W2EXT 80

// bf16 round-to-nearest-even, returns low 16 bits
__device__ __forceinline__ u32 bf16rne(float f) {
    u32 u = __float_as_uint(f);
    return (u + 0x7fffu + ((u >> 16) & 1u)) >> 16;
}

// leaky_relu(s) == max(s, SLOPE*s) for 0 < SLOPE < 1
#define LR(s) fmaxf((s), SLOPE * (s))

// ---------------------------------------------------------------------------
// Phase 1: LDS-staged radix partition over the NE random edges only.
// ---------------------------------------------------------------------------
__global__ __launch_bounds__(256) void k_bin(
    const int* __restrict__ ei, int* __restrict__ cnt, u32* __restrict__ staging)
{
    __shared__ u32 lbuf[NB * LCAP];   // 50176 B
    __shared__ int lcnt[NB];
    __shared__ int gbase[NB];
    const int t = threadIdx.x;
    const int e0 = blockIdx.x * EPB;

    for (int i = t; i < NB; i += 256) lcnt[i] = 0;
    __syncthreads();

    for (int i = t; i < EPB; i += 256) {
        const int e = e0 + i;
        if (e >= NE) break;
        const int src = ei[e];
        const int dst = ei[NE + e];
        const int b = dst >> 8;
        const int p = atomicAdd(&lcnt[b], 1);       // LDS atomic (cheap)
        lbuf[b * LCAP + p] = ((u32)(dst & 255) << 16) | (u32)src;
    }
    __syncthreads();

    for (int i = t; i < NB; i += 256)
        gbase[i] = atomicAdd(&cnt[i * CPAD], lcnt[i]);
    __syncthreads();

    // flush: thread = bucket; sequential stores -> lines merge in L2
    for (int b = t; b < NB; b += 256) {
        const int n = lcnt[b];
        const int gb = gbase[b];
        u32* dstp = staging + (size_t)b * CAPB + gb;
        const u32* srcp = lbuf + b * LCAP;
        for (int j = 0; j < n; ++j) dstp[j] = srcp[j];
    }
}

// ---------------------------------------------------------------------------
// Phase 2: one block per bucket, FIXED base b*BSTRIDE (no cross-bucket scan).
// Rows padded to multiples of 8 with null-node entries; self-loop first.
// ---------------------------------------------------------------------------
__global__ __launch_bounds__(1024) void k_place(
    const int* __restrict__ cnt, const u32* __restrict__ staging,
    int* __restrict__ rowptr, int* __restrict__ rowend,
    u16* __restrict__ sorted16)
{
    __shared__ int hist[256];
    __shared__ int cur[256];
    __shared__ int scan[256];
    const int b = blockIdx.x;
    const int t = threadIdx.x;
    const int tot = cnt[b * CPAD];
    const int base = b * BSTRIDE;

    if (t < 256) hist[t] = ((b * 256 + t) < NN) ? 1 : 0;   // seed self-loop
    __syncthreads();

    for (int i = t; i < tot; i += 1024)
        atomicAdd(&hist[staging[(size_t)b * CAPB + i] >> 16], 1);
    __syncthreads();

    if (t < 256) scan[t] = (hist[t] + 7) & ~7;   // padded counts
    __syncthreads();
    for (int off = 1; off < 256; off <<= 1) {
        int v = 0;
        if (t < 256 && t >= off) v = scan[t - off];
        __syncthreads();
        if (t < 256) scan[t] += v;
        __syncthreads();
    }
    if (t < 256) {
        const int padded = (hist[t] + 7) & ~7;
        const int excl = (t == 0) ? 0 : scan[t - 1];
        const int node = b * 256 + t;
        if (node < NN) {
            rowptr[node] = base + excl;
            rowend[node] = base + excl + padded;       // padded end
            sorted16[base + excl] = (u16)node;         // self-loop first
            for (int j = hist[t]; j < padded; ++j)     // null-pad tail
                sorted16[base + excl + j] = (u16)NN;
            cur[t] = excl + 1;
        } else {
            cur[t] = excl;
        }
    }
    __syncthreads();
    for (int i = t; i < tot; i += 1024) {
        const u32 v = staging[(size_t)b * CAPB + i];
        const int pos = atomicAdd(&cur[v >> 16], 1);
        sorted16[base + pos] = (u16)(v & 0xffffu);
    }
}

// ---------------------------------------------------------------------------
// Weight prep: build EXTENDED transposed bf16 weights Wt[j][k] (k contiguous).
// Also zero cnt and init null-node entries.
// ---------------------------------------------------------------------------
__global__ __launch_bounds__(256) void k_wprep(
    const float* __restrict__ W1, const float* __restrict__ W2,
    const float* __restrict__ as1w, const float* __restrict__ ad1w,
    const float* __restrict__ as2w, const float* __restrict__ ad2w,
    u16* __restrict__ Wt1, u16* __restrict__ Wt2, int* __restrict__ cnt,
    u32* __restrict__ h1b, float* __restrict__ as1, float* __restrict__ as2)
{
    const int i = blockIdx.x * 256 + threadIdx.x;
    if (i < NB * CPAD) cnt[i] = 0;
    if (i < 64) h1b[(size_t)64 * NN + i] = 0;          // null h1 row (finite)
    if (i < 8)  as1[(size_t)NH * NN + i] = -1e30f;     // null alpha_src L1
    if (i == 8) as2[NN] = -1e30f;                      // null alpha_src L2

    if (i < W1EXT * 128) {
        const int j = i >> 7, k = i & 127;
        float v;
        if (j < 128) {
            v = W1[k * 128 + j];
        } else if (j < 136) {
            const int h = j - 128;
            v = 0.f;
            for (int c = 0; c < 16; ++c)
                v += W1[k * 128 + h * 16 + c] * as1w[h * 16 + c];
        } else {
            const int h = j - 136;
            v = 0.f;
            for (int c = 0; c < 16; ++c)
                v += W1[k * 128 + h * 16 + c] * ad1w[h * 16 + c];
        }
        Wt1[j * 128 + k] = (u16)bf16rne(v);
    } else if (i < W1EXT * 128 + W2EXT * 128) {
        const int i2 = i - W1EXT * 128;
        const int j = i2 >> 7, k = i2 & 127;
        float v = 0.f;
        if (j < 64) {
            v = W2[k * 64 + j];
        } else if (j == 64) {
            for (int c = 0; c < 64; ++c) v += W2[k * 64 + c] * as2w[c];
        } else if (j == 65) {
            for (int c = 0; c < 64; ++c) v += W2[k * 64 + c] * ad2w[c];
        }
        Wt2[j * 128 + k] = (u16)bf16rne(v);
    }
}

// ---------------------------------------------------------------------------
// MFMA GEMM1: [h1 | as1 | ad1] = x @ W1ext (50000x128 @ 128x144).
// Block: 128 rows x 144 cols, 8 waves (512 thr). LDS 68 KB -> 2 blocks/CU
// (16 waves/CU, ~2x round-4 residency); 391 blocks halves W re-staging.
// ---------------------------------------------------------------------------
__global__ __launch_bounds__(512) void k_gemm1(
    const float* __restrict__ x, const u16* __restrict__ Wt1,
    u16* __restrict__ h1s, float* __restrict__ as1, float* __restrict__ ad1)
{
    __shared__ u32 xb[128 * 64];     // 32 KB: 128 rows x 16 chunks x 16B (swizzled)
    __shared__ u32 Wb[W1EXT * 64];   // 36 KB
    const int tid = threadIdx.x;
    const int row0 = blockIdx.x * 128;

    {   // stage Wb from Wt1 (bf16 [j][k]): 2304 chunks over 512 threads
        const uint4* Wt = (const uint4*)Wt1;
        for (int p = 0; p < 5; ++p) {
            const int id = p * 512 + tid;
            if (id < W1EXT * 16) {
                const int n = id >> 4, c = id & 15;
                *(uint4*)(Wb + n * 64 + ((c ^ (n & 15)) << 2)) = Wt[n * 16 + c];
            }
        }
    }
    for (int p = 0; p < 4; ++p) {    // 2048 chunks of xb
        const int id = p * 512 + tid;
        const int m = id >> 4, c = id & 15;
        const int row = row0 + m;
        uint4 v = make_uint4(0, 0, 0, 0);
        if (row < NN) {
            const float4 f0 = *(const float4*)(x + (size_t)row * 128 + c * 8);
            const float4 f1 = *(const float4*)(x + (size_t)row * 128 + c * 8 + 4);
            v.x = bf16rne(f0.x) | (bf16rne(f0.y) << 16);
            v.y = bf16rne(f0.z) | (bf16rne(f0.w) << 16);
            v.z = bf16rne(f1.x) | (bf16rne(f1.y) << 16);
            v.w = bf16rne(f1.z) | (bf16rne(f1.w) << 16);
        }
        *(uint4*)(xb + m * 64 + ((c ^ (m & 15)) << 2)) = v;
    }
    __syncthreads();

    const int w = tid >> 6, lane = tid & 63;   // w = 0..7 -> rows 16w..16w+15
    const int nl = lane & 15, quad = lane >> 4;
    f32x4 acc[9] = {};
    for (int kk = 0; kk < 4; ++kk) {
        const int cm = kk * 4 + quad;
        const bf16x8 a = *(const bf16x8*)(xb + (16 * w + nl) * 64 + ((cm ^ nl) << 2));
#pragma unroll
        for (int tn = 0; tn < 9; ++tn) {
            const bf16x8 b = *(const bf16x8*)(Wb + (16 * tn + nl) * 64 + ((cm ^ nl) << 2));
            acc[tn] = __builtin_amdgcn_mfma_f32_16x16x32_bf16(a, b, acc[tn], 0, 0, 0);
        }
    }

#pragma unroll
    for (int tn = 0; tn < 8; ++tn) {
#pragma unroll
        for (int r = 0; r < 4; ++r) {
            const int row = row0 + 16 * w + quad * 4 + r;   // uniform in 16-lane group
            if (row < NN)
                h1s[(size_t)row * 128 + 16 * tn + nl] = (u16)bf16rne(acc[tn][r]);
        }
    }
#pragma unroll
    for (int r = 0; r < 4; ++r) {   // tile 8: cols 128..143 = [as1 | ad1]
        const int row = row0 + 16 * w + quad * 4 + r;
        if (row < NN) {
            const float v = acc[8][r];
            if (nl < 8) as1[row * NH + nl] = v;
            else        ad1[row * NH + (nl - 8)] = v;
        }
    }
}

// ---------------------------------------------------------------------------
// MFMA GEMM2: [h2 | as2 | ad2] = act2 @ W2ext (50000x128 @ 128x80).
// Block: 128 rows x 80 cols, 8 waves. LDS 52 KB -> 3 blocks/CU.
// ---------------------------------------------------------------------------
__global__ __launch_bounds__(512) void k_gemm2(
    const u32* __restrict__ act2b, const u16* __restrict__ Wt2,
    u16* __restrict__ h2s, float* __restrict__ as2, float* __restrict__ ad2)
{
    __shared__ u32 xb[128 * 64];     // 32 KB
    __shared__ u32 Wb[W2EXT * 64];   // 20 KB
    const int tid = threadIdx.x;
    const int row0 = blockIdx.x * 128;

    {   // stage Wb from Wt2: 1280 chunks over 512 threads
        const uint4* Wt = (const uint4*)Wt2;
        for (int p = 0; p < 3; ++p) {
            const int id = p * 512 + tid;
            if (id < W2EXT * 16) {
                const int n = id >> 4, c = id & 15;
                *(uint4*)(Wb + n * 64 + ((c ^ (n & 15)) << 2)) = Wt[n * 16 + c];
            }
        }
    }
    for (int p = 0; p < 4; ++p) {    // 2048 chunks of xb (bf16 row-major input)
        const int id = p * 512 + tid;
        const int m = id >> 4, c = id & 15;
        const int row = row0 + m;
        uint4 v = make_uint4(0, 0, 0, 0);
        if (row < NN) v = ((const uint4*)act2b)[(size_t)row * 16 + c];
        *(uint4*)(xb + m * 64 + ((c ^ (m & 15)) << 2)) = v;
    }
    __syncthreads();

    const int w = tid >> 6, lane = tid & 63;
    const int nl = lane & 15, quad = lane >> 4;
    f32x4 acc[5] = {};
    for (int kk = 0; kk < 4; ++kk) {
        const int cm = kk * 4 + quad;
        const bf16x8 a = *(const bf16x8*)(xb + (16 * w + nl) * 64 + ((cm ^ nl) << 2));
#pragma unroll
        for (int tn = 0; tn < 5; ++tn) {
            const bf16x8 b = *(const bf16x8*)(Wb + (16 * tn + nl) * 64 + ((cm ^ nl) << 2));
            acc[tn] = __builtin_amdgcn_mfma_f32_16x16x32_bf16(a, b, acc[tn], 0, 0, 0);
        }
    }

#pragma unroll
    for (int tn = 0; tn < 4; ++tn) {
#pragma unroll
        for (int r = 0; r < 4; ++r) {
            const int row = row0 + 16 * w + quad * 4 + r;   // uniform in 16-lane group
            if (row < NN)
                h2s[(size_t)row * 64 + 16 * tn + nl] = (u16)bf16rne(acc[tn][r]);
        }
    }
#pragma unroll
    for (int r = 0; r < 4; ++r) {   // tile 4: col 64 = as2, col 65 = ad2
        const int row = row0 + 16 * w + quad * 4 + r;
        if (row < NN) {
            const float v = acc[4][r];
            if (nl == 0) as2[row] = v;
            else if (nl == 1) ad2[row] = v;
        }
    }
}

// ---------------------------------------------------------------------------
// Aggregation layer 1: one node per wave. Rows are 8-padded -> every group is
// one uint4 pack (wave-uniform 16B load). Lane-split exp (lane = j*8+h does
// edge j, head h; one exp instr per 8 edges), bpermute to distribute.
// 2-stage software pipeline: 16 row-gathers in flight.
// ---------------------------------------------------------------------------
#define PG1(KK, S, G, WJ) do {                                                \
    const uint4 p = *(const uint4*)(sorted16 + (KK));                         \
    S[0] = p.x & 0xffffu; S[1] = p.x >> 16;                                   \
    S[2] = p.y & 0xffffu; S[3] = p.y >> 16;                                   \
    S[4] = p.z & 0xffffu; S[5] = p.z >> 16;                                   \
    S[6] = p.w & 0xffffu; S[7] = p.w >> 16;                                   \
    const u32 hlf = (head & 4) ? ((head & 2) ? p.w : p.z)                     \
                               : ((head & 2) ? p.y : p.x);                    \
    const u32 sj = (head & 1) ? (hlf >> 16) : (hlf & 0xffffu);                \
    WJ = __expf(LR(as1[sj * NH + eh] + adeh));                                \
    _Pragma("unroll") for (int j = 0; j < 8; ++j)                             \
        G[j] = h1b[S[j] * 64 + lane];                                         \
} while (0)

#define CONS1(G, WJ) do {                                                     \
    _Pragma("unroll") for (int j = 0; j < 8; ++j) {                           \
        const float wv = __uint_as_float((u32)__builtin_amdgcn_ds_bpermute(   \
            h4 + j * 32, (int)__float_as_uint(WJ)));                          \
        acc0 += wv * __uint_as_float(G[j] << 16);                             \
        acc1 += wv * __uint_as_float(G[j] & 0xffff0000u);                     \
        den  += wv; }                                                         \
} while (0)

__global__ __launch_bounds__(256) void k_agg1(
    const int* __restrict__ rowptr, const int* __restrict__ rowend,
    const u16* __restrict__ sorted16,
    const u32* __restrict__ h1b, const float* __restrict__ as1,
    const float* __restrict__ ad1,
    u32* __restrict__ act2b)
{
    const int node = blockIdx.x * 4 + (threadIdx.x >> 6);
    const int lane = threadIdx.x & 63;
    const int head = lane >> 3;          // accumulation head (channels 16h..)
    const int eh   = lane & 7;           // exp-role head
    const float adeh = ad1[node * NH + eh];
    const int k0 = rowptr[node], kend = rowend[node];   // kend-k0 multiple of 8, >=8
    const int h4 = head << 2;
    float acc0 = 0.f, acc1 = 0.f, den = 0.f;
    u32 sA[8], gA[8], sB[8], gB[8];
    float wA, wB;

    PG1(k0, sA, gA, wA);
    int k = k0 + 8;
    while (k + 16 <= kend) {
        PG1(k, sB, gB, wB);      CONS1(gA, wA);
        PG1(k + 8, sA, gA, wA);  CONS1(gB, wB);
        k += 16;
    }
    if (k < kend) {
        PG1(k, sB, gB, wB);  CONS1(gA, wA);  CONS1(gB, wB);
    } else {
        CONS1(gA, wA);
    }

    const float inv = 1.f / den;                    // self-loop => den > 0
    float v0 = acc0 * inv, v1 = acc1 * inv;
    v0 = v0 > 0.f ? v0 : expm1f(v0);                // ELU
    v1 = v1 > 0.f ? v1 : expm1f(v1);
    act2b[node * 64 + lane] = bf16rne(v0) | (bf16rne(v1) << 16);
}

// ---------------------------------------------------------------------------
// Aggregation layer 2 (fused edge weights) + log_softmax. Lane l computes the
// weight for edge (l&7) of the group (one exp instr / 8 edges); bpermute from
// lanes 0..7 broadcasts. Same uint4 packs + 2-stage pipeline.
// ---------------------------------------------------------------------------
#define PG2(KK, S, G, WJ) do {                                                \
    const uint4 p = *(const uint4*)(sorted16 + (KK));                         \
    S[0] = p.x & 0xffffu; S[1] = p.x >> 16;                                   \
    S[2] = p.y & 0xffffu; S[3] = p.y >> 16;                                   \
    S[4] = p.z & 0xffffu; S[5] = p.z >> 16;                                   \
    S[6] = p.w & 0xffffu; S[7] = p.w >> 16;                                   \
    const u32 hlf = (lane & 4) ? ((lane & 2) ? p.w : p.z)                     \
                               : ((lane & 2) ? p.y : p.x);                    \
    const u32 sj = (lane & 1) ? (hlf >> 16) : (hlf & 0xffffu);                \
    WJ = __expf(LR(as2[sj] + adv));                                           \
    _Pragma("unroll") for (int j = 0; j < 8; ++j)                             \
        G[j] = h2s[S[j] * 64 + lane];                                         \
} while (0)

#define CONS2(G, WJ) do {                                                     \
    _Pragma("unroll") for (int j = 0; j < 8; ++j) {                           \
        const float wv = __uint_as_float((u32)__builtin_amdgcn_ds_bpermute(   \
            j << 2, (int)__float_as_uint(WJ)));                               \
        acc += wv * __uint_as_float(((u32)G[j]) << 16);                       \
        den += wv; }                                                          \
} while (0)

__global__ __launch_bounds__(256) void k_agg2(
    const int* __restrict__ rowptr, const int* __restrict__ rowend,
    const u16* __restrict__ sorted16,
    const u16* __restrict__ h2s, const float* __restrict__ as2,
    const float* __restrict__ ad2,
    float* __restrict__ out)
{
    const int node = blockIdx.x * 4 + (threadIdx.x >> 6);
    const int lane = threadIdx.x & 63;
    const float adv = ad2[node];
    const int k0 = rowptr[node], kend = rowend[node];
    float acc = 0.f, den = 0.f;
    u32 sA[8], gA[8], sB[8], gB[8];
    float wA, wB;

    PG2(k0, sA, gA, wA);
    int k = k0 + 8;
    while (k + 16 <= kend) {
        PG2(k, sB, gB, wB);      CONS2(gA, wA);
        PG2(k + 8, sA, gA, wA);  CONS2(gB, wB);
        k += 16;
    }
    if (k < kend) {
        PG2(k, sB, gB, wB);  CONS2(gA, wA);  CONS2(gB, wB);
    } else {
        CONS2(gA, wA);
    }

    const float v = acc / den;
    float m = v;
    for (int kk = 1; kk < 64; kk <<= 1) m = fmaxf(m, __shfl_xor(m, kk));
    float se = __expf(v - m);
    for (int kk = 1; kk < 64; kk <<= 1) se += __shfl_xor(se, kk);
    out[node * 64 + lane] = v - m - logf(se);
}

// ---------------------------------------------------------------------------
// Workspace layout (u32 units, 64B-aligned chunks).
// ---------------------------------------------------------------------------
extern "C" void kernel_launch(void* const* d_in, const int* in_sizes, int n_in,
                              void* d_out, int out_size, void* d_ws, size_t ws_size,
                              hipStream_t stream)
{
    (void)in_sizes; (void)n_in; (void)out_size; (void)ws_size;
    const float* x    = (const float*)d_in[0];
    const int*   ei   = (const int*)d_in[1];
    const float* W1   = (const float*)d_in[2];
    const float* as1w = (const float*)d_in[3];
    const float* ad1w = (const float*)d_in[4];
    const float* W2   = (const float*)d_in[6];
    const float* as2w = (const float*)d_in[7];
    const float* ad2w = (const float*)d_in[8];
    float* out = (float*)d_out;

    u32* ws = (u32*)d_ws;
    size_t o = 0;
    auto take = [&](size_t n) { size_t r = o; o += (n + 15) & ~(size_t)15; return r; };

    u32*   h1b      = ws + take((size_t)64 * (NN + 1));
    float* as1      = (float*)(ws + take((size_t)NH * NN + 8));
    float* ad1      = (float*)(ws + take((size_t)NH * NN));
    u32*   act2b    = ws + take((size_t)64 * NN);
    float* as2      = (float*)(ws + take(NN + 1));
    float* ad2      = (float*)(ws + take(NN));
    int*   rowptr   = (int*)(ws + take(NN));
    int*   rowend   = (int*)(ws + take(NN));
    u16*   sorted16 = (u16*)(ws + take(((size_t)NB * BSTRIDE + 1) / 2));
    u32*   staging  = ws + take((size_t)NB * CAPB);
    int*   cnt      = (int*)(ws + take(NB * CPAD));
    u16*   Wt1      = (u16*)(ws + take((size_t)W1EXT * 128 / 2));
    u16*   Wt2      = (u16*)(ws + take((size_t)W2EXT * 128 / 2));
    u16*   h1s      = (u16*)h1b;
    u16*   h2s      = (u16*)h1b;          // alias (h1 dead after agg1)

    k_wprep<<<112, 256, 0, stream>>>(W1, W2, as1w, ad1w, as2w, ad2w,
                                     Wt1, Wt2, cnt, h1b, as1, as2);
    k_bin  <<<NBB, 256, 0, stream>>>(ei, cnt, staging);
    k_place<<<NB, 1024, 0, stream>>>(cnt, staging, rowptr, rowend, sorted16);

    k_gemm1<<<391, 512, 0, stream>>>(x, Wt1, h1s, as1, ad1);
    k_agg1 <<<NN / 4, 256, 0, stream>>>(rowptr, rowend, sorted16, h1b, as1, ad1, act2b);
    k_gemm2<<<391, 512, 0, stream>>>(act2b, Wt2, h2s, as2, ad2);
    k_agg2 <<<NN / 4, 256, 0, stream>>>(rowptr, rowend, sorted16, h2s, as2, ad2, out);
}

// Round 6
// 183.476 us; speedup vs baseline: 1.4179x; 1.0420x over previous
//
#include <hip/hip_runtime.h>
#include <math.h>

typedef unsigned int  u32;
typedef unsigned short u16;
typedef short bf16x8 __attribute__((ext_vector_type(8)));   // 8 bf16 = 4 VGPRs
typedef float f32x4  __attribute__((ext_vector_type(4)));

// Problem constants (match reference)
#define NN    50000
#define NE    800000
#define ET    (NE + NN)     // edges + self loops = 850000
#define IND   128
#define HIDD  128
#define NH    8
#define OD    64
#define SLOPE 0.2f

// Binned counting sort parameters. Self-loops are NOT staged (deterministic,
// k_place inserts them directly). Rows are padded to 8-edge groups with a
// NULL node (id NN) whose weight is exactly 0 -> no tail loops, uint4 packs.
#define NB    196           // buckets of 256 nodes: ceil(50000/256)
#define EPB   4096          // edges per binning block
#define NBB   ((NE + EPB - 1) / EPB)   // 196 binning blocks (random edges only)
#define LCAP  64            // LDS cap per (block,bucket): mean 21, +9.4 sigma
#define CAPB  5120          // global cap per bucket: mean 4082, +13 sigma
#define CPAD  16            // counter stride in ints (64 B = own cache line)
#define BSTRIDE 7168        // fixed padded bucket stride (mean ~5248, +26 sigma)

// Extended GEMM widths: alpha reductions folded in as extra columns.
// GEMM1: cols 0..127 = W1, 128..135 = W1@a_src per head, 136..143 = W1@a_dst.
// GEMM2: cols 0..63 = W2, 64 = W2@a_src2, 65 = W2@a_dst2, 66..79 = 0.
#define W1EXT 144
#define W2EXT 80
#define WPB   112           // wprep blocks (covers (W1EXT+W2EXT)*128 = 28672)
#define G1B   391           // gemm blocks: ceil(50000/128)

// bf16 round-to-nearest-even, returns low 16 bits
__device__ __forceinline__ u32 bf16rne(float f) {
    u32 u = __float_as_uint(f);
    return (u + 0x7fffu + ((u >> 16) & 1u)) >> 16;
}

// leaky_relu(s) == max(s, SLOPE*s) for 0 < SLOPE < 1
#define LR(s) fmaxf((s), SLOPE * (s))

// ---------------------------------------------------------------------------
// Fused launch 1: blocks 0..NBB-1 = edge binning (LDS-staged radix partition);
// blocks NBB.. = weight prep (extended transposed bf16 weights + null inits).
// cnt is zeroed by hipMemsetAsync before this launch (bin atomics need it).
// ---------------------------------------------------------------------------
__global__ __launch_bounds__(256) void k_prep_bin(
    const int* __restrict__ ei, int* __restrict__ cnt, u32* __restrict__ staging,
    const float* __restrict__ W1, const float* __restrict__ W2,
    const float* __restrict__ as1w, const float* __restrict__ ad1w,
    const float* __restrict__ as2w, const float* __restrict__ ad2w,
    u16* __restrict__ Wt1, u16* __restrict__ Wt2,
    u32* __restrict__ h1b, float* __restrict__ as1, float* __restrict__ as2)
{
    __shared__ u32 lbuf[NB * LCAP];   // 50176 B (bin path only)
    __shared__ int lcnt[NB];
    __shared__ int gbase[NB];
    const int t = threadIdx.x;

    if (blockIdx.x >= NBB) {
        // ---- weight-prep path ----
        const int i = (blockIdx.x - NBB) * 256 + t;
        if (i < 64) h1b[(size_t)64 * NN + i] = 0;          // null h1 row
        if (i < 8)  as1[(size_t)NH * NN + i] = -1e30f;     // null alpha_src L1
        if (i == 8) as2[NN] = -1e30f;                      // null alpha_src L2

        if (i < W1EXT * 128) {
            const int j = i >> 7, k = i & 127;
            float v;
            if (j < 128) {
                v = W1[k * 128 + j];
            } else if (j < 136) {
                const int h = j - 128;
                v = 0.f;
                for (int c = 0; c < 16; ++c)
                    v += W1[k * 128 + h * 16 + c] * as1w[h * 16 + c];
            } else {
                const int h = j - 136;
                v = 0.f;
                for (int c = 0; c < 16; ++c)
                    v += W1[k * 128 + h * 16 + c] * ad1w[h * 16 + c];
            }
            Wt1[j * 128 + k] = (u16)bf16rne(v);
        } else if (i < W1EXT * 128 + W2EXT * 128) {
            const int i2 = i - W1EXT * 128;
            const int j = i2 >> 7, k = i2 & 127;
            float v = 0.f;
            if (j < 64) {
                v = W2[k * 64 + j];
            } else if (j == 64) {
                for (int c = 0; c < 64; ++c) v += W2[k * 64 + c] * as2w[c];
            } else if (j == 65) {
                for (int c = 0; c < 64; ++c) v += W2[k * 64 + c] * ad2w[c];
            }
            Wt2[j * 128 + k] = (u16)bf16rne(v);
        }
        return;
    }

    // ---- binning path ----
    const int e0 = blockIdx.x * EPB;
    for (int i = t; i < NB; i += 256) lcnt[i] = 0;
    __syncthreads();

    for (int i = t; i < EPB; i += 256) {
        const int e = e0 + i;
        if (e >= NE) break;
        const int src = ei[e];
        const int dst = ei[NE + e];
        const int b = dst >> 8;
        const int p = atomicAdd(&lcnt[b], 1);       // LDS atomic (cheap)
        lbuf[b * LCAP + p] = ((u32)(dst & 255) << 16) | (u32)src;
    }
    __syncthreads();

    for (int i = t; i < NB; i += 256)
        gbase[i] = atomicAdd(&cnt[i * CPAD], lcnt[i]);
    __syncthreads();

    // flush: thread = bucket; sequential stores -> lines merge in L2
    for (int b = t; b < NB; b += 256) {
        const int n = lcnt[b];
        const int gb = gbase[b];
        u32* dstp = staging + (size_t)b * CAPB + gb;
        const u32* srcp = lbuf + b * LCAP;
        for (int j = 0; j < n; ++j) dstp[j] = srcp[j];
    }
}

// ---------------------------------------------------------------------------
// Fused launch 2: blocks 0..NB-1 = k_place (CSR build, 8-padded rows, fixed
// bucket base); blocks NB.. = MFMA GEMM1 [h1|as1|ad1] = x @ W1ext
// (50000x128 @ 128x144), 128 rows x 8 waves. place depends only on bin,
// gemm1 only on wprep -> they overlap inside one dispatch.
// GEMM epilogue: fragments -> LDS (xb, dead after MFMA) -> coalesced uint4
// stores (replaces 32 scattered 2B global stores per wave).
// ---------------------------------------------------------------------------
__global__ __launch_bounds__(512) void k_place_gemm1(
    const int* __restrict__ cnt, const u32* __restrict__ staging,
    int* __restrict__ rowptr, int* __restrict__ rowend,
    u16* __restrict__ sorted16,
    const float* __restrict__ x, const u16* __restrict__ Wt1,
    u16* __restrict__ h1s, float* __restrict__ as1, float* __restrict__ ad1)
{
    __shared__ u32 xb[128 * 64];     // 32 KB (gemm: A tile, then C staging)
    __shared__ u32 Wb[W1EXT * 64];   // 36 KB
    const int tid = threadIdx.x;

    if (blockIdx.x < NB) {
        // ---- place path (512 threads; LDS carved from xb) ----
        int* hist = (int*)xb;
        int* cur  = hist + 256;
        int* scan = cur + 256;
        const int b = blockIdx.x;
        const int tot = cnt[b * CPAD];
        const int base = b * BSTRIDE;

        if (tid < 256) hist[tid] = ((b * 256 + tid) < NN) ? 1 : 0;  // self-loop
        __syncthreads();

        for (int i = tid; i < tot; i += 512)
            atomicAdd(&hist[staging[(size_t)b * CAPB + i] >> 16], 1);
        __syncthreads();

        if (tid < 256) scan[tid] = (hist[tid] + 7) & ~7;   // padded counts
        __syncthreads();
        for (int off = 1; off < 256; off <<= 1) {
            int v = 0;
            if (tid < 256 && tid >= off) v = scan[tid - off];
            __syncthreads();
            if (tid < 256) scan[tid] += v;
            __syncthreads();
        }
        if (tid < 256) {
            const int padded = (hist[tid] + 7) & ~7;
            const int excl = (tid == 0) ? 0 : scan[tid - 1];
            const int node = b * 256 + tid;
            if (node < NN) {
                rowptr[node] = base + excl;
                rowend[node] = base + excl + padded;       // padded end
                sorted16[base + excl] = (u16)node;         // self-loop first
                for (int j = hist[tid]; j < padded; ++j)   // null-pad tail
                    sorted16[base + excl + j] = (u16)NN;
                cur[tid] = excl + 1;
            } else {
                cur[tid] = excl;
            }
        }
        __syncthreads();
        for (int i = tid; i < tot; i += 512) {
            const u32 v = staging[(size_t)b * CAPB + i];
            const int pos = atomicAdd(&cur[v >> 16], 1);
            sorted16[base + pos] = (u16)(v & 0xffffu);
        }
        return;
    }

    // ---- gemm1 path ----
    const int row0 = (blockIdx.x - NB) * 128;

    {   // stage Wb from Wt1 (bf16 [j][k]): 2304 chunks over 512 threads
        const uint4* Wt = (const uint4*)Wt1;
        for (int p = 0; p < 5; ++p) {
            const int id = p * 512 + tid;
            if (id < W1EXT * 16) {
                const int n = id >> 4, c = id & 15;
                *(uint4*)(Wb + n * 64 + ((c ^ (n & 15)) << 2)) = Wt[n * 16 + c];
            }
        }
    }
    for (int p = 0; p < 4; ++p) {    // 2048 chunks of xb
        const int id = p * 512 + tid;
        const int m = id >> 4, c = id & 15;
        const int row = row0 + m;
        uint4 v = make_uint4(0, 0, 0, 0);
        if (row < NN) {
            const float4 f0 = *(const float4*)(x + (size_t)row * 128 + c * 8);
            const float4 f1 = *(const float4*)(x + (size_t)row * 128 + c * 8 + 4);
            v.x = bf16rne(f0.x) | (bf16rne(f0.y) << 16);
            v.y = bf16rne(f0.z) | (bf16rne(f0.w) << 16);
            v.z = bf16rne(f1.x) | (bf16rne(f1.y) << 16);
            v.w = bf16rne(f1.z) | (bf16rne(f1.w) << 16);
        }
        *(uint4*)(xb + m * 64 + ((c ^ (m & 15)) << 2)) = v;
    }
    __syncthreads();

    const int w = tid >> 6, lane = tid & 63;   // w = 0..7 -> rows 16w..16w+15
    const int nl = lane & 15, quad = lane >> 4;
    f32x4 acc[9] = {};
    for (int kk = 0; kk < 4; ++kk) {
        const int cm = kk * 4 + quad;
        const bf16x8 a = *(const bf16x8*)(xb + (16 * w + nl) * 64 + ((cm ^ nl) << 2));
#pragma unroll
        for (int tn = 0; tn < 9; ++tn) {
            const bf16x8 b = *(const bf16x8*)(Wb + (16 * tn + nl) * 64 + ((cm ^ nl) << 2));
            acc[tn] = __builtin_amdgcn_mfma_f32_16x16x32_bf16(a, b, acc[tn], 0, 0, 0);
        }
    }

    __syncthreads();                 // all xb reads done -> reuse as C staging
    {   // h1 fragments -> LDS row-major u16 [128][128]
        u16* h1ld = (u16*)xb;
#pragma unroll
        for (int tn = 0; tn < 8; ++tn) {
#pragma unroll
            for (int r = 0; r < 4; ++r) {
                const int row = 16 * w + quad * 4 + r;
                h1ld[row * 128 + 16 * tn + nl] = (u16)bf16rne(acc[tn][r]);
            }
        }
    }
#pragma unroll
    for (int r = 0; r < 4; ++r) {    // tile 8: cols 128..143 = [as1 | ad1]
        const int row = row0 + 16 * w + quad * 4 + r;
        if (row < NN) {
            const float v = acc[8][r];
            if (nl < 8) as1[row * NH + nl] = v;
            else        ad1[row * NH + (nl - 8)] = v;
        }
    }
    __syncthreads();
    // coalesced h1 store: 2048 uint4 chunks, 4 per thread
    for (int p = 0; p < 4; ++p) {
        const int id = p * 512 + tid;
        const int row = id >> 4, c = id & 15;
        const int grow = row0 + row;
        if (grow < NN)
            ((uint4*)h1s)[(size_t)grow * 16 + c] = ((const uint4*)xb)[row * 16 + c];
    }
}

// ---------------------------------------------------------------------------
// MFMA GEMM2: [h2 | as2 | ad2] = act2 @ W2ext (50000x128 @ 128x80).
// Same coalesced-epilogue structure as gemm1.
// ---------------------------------------------------------------------------
__global__ __launch_bounds__(512) void k_gemm2(
    const u32* __restrict__ act2b, const u16* __restrict__ Wt2,
    u16* __restrict__ h2s, float* __restrict__ as2, float* __restrict__ ad2)
{
    __shared__ u32 xb[128 * 64];     // 32 KB
    __shared__ u32 Wb[W2EXT * 64];   // 20 KB
    const int tid = threadIdx.x;
    const int row0 = blockIdx.x * 128;

    {   // stage Wb from Wt2: 1280 chunks over 512 threads
        const uint4* Wt = (const uint4*)Wt2;
        for (int p = 0; p < 3; ++p) {
            const int id = p * 512 + tid;
            if (id < W2EXT * 16) {
                const int n = id >> 4, c = id & 15;
                *(uint4*)(Wb + n * 64 + ((c ^ (n & 15)) << 2)) = Wt[n * 16 + c];
            }
        }
    }
    for (int p = 0; p < 4; ++p) {    // 2048 chunks of xb (bf16 row-major input)
        const int id = p * 512 + tid;
        const int m = id >> 4, c = id & 15;
        const int row = row0 + m;
        uint4 v = make_uint4(0, 0, 0, 0);
        if (row < NN) v = ((const uint4*)act2b)[(size_t)row * 16 + c];
        *(uint4*)(xb + m * 64 + ((c ^ (m & 15)) << 2)) = v;
    }
    __syncthreads();

    const int w = tid >> 6, lane = tid & 63;
    const int nl = lane & 15, quad = lane >> 4;
    f32x4 acc[5] = {};
    for (int kk = 0; kk < 4; ++kk) {
        const int cm = kk * 4 + quad;
        const bf16x8 a = *(const bf16x8*)(xb + (16 * w + nl) * 64 + ((cm ^ nl) << 2));
#pragma unroll
        for (int tn = 0; tn < 5; ++tn) {
            const bf16x8 b = *(const bf16x8*)(Wb + (16 * tn + nl) * 64 + ((cm ^ nl) << 2));
            acc[tn] = __builtin_amdgcn_mfma_f32_16x16x32_bf16(a, b, acc[tn], 0, 0, 0);
        }
    }

    __syncthreads();                 // all xb reads done -> reuse as C staging
    {   // h2 fragments -> LDS row-major u16 [128][64]
        u16* h2ld = (u16*)xb;
#pragma unroll
        for (int tn = 0; tn < 4; ++tn) {
#pragma unroll
            for (int r = 0; r < 4; ++r) {
                const int row = 16 * w + quad * 4 + r;
                h2ld[row * 64 + 16 * tn + nl] = (u16)bf16rne(acc[tn][r]);
            }
        }
    }
#pragma unroll
    for (int r = 0; r < 4; ++r) {    // tile 4: col 64 = as2, col 65 = ad2
        const int row = row0 + 16 * w + quad * 4 + r;
        if (row < NN) {
            const float v = acc[4][r];
            if (nl == 0) as2[row] = v;
            else if (nl == 1) ad2[row] = v;
        }
    }
    __syncthreads();
    // coalesced h2 store: 1024 uint4 chunks, 2 per thread
    for (int p = 0; p < 2; ++p) {
        const int id = p * 512 + tid;
        const int row = id >> 3, c = id & 7;
        const int grow = row0 + row;
        if (grow < NN)
            ((uint4*)h2s)[(size_t)grow * 8 + c] = ((const uint4*)xb)[row * 8 + c];
    }
}

// ---------------------------------------------------------------------------
// Aggregation layer 1: one node per wave. Rows are 8-padded -> every group is
// one uint4 pack (wave-uniform 16B load). Lane-split exp (lane = j*8+h does
// edge j, head h; one exp instr per 8 edges), bpermute to distribute.
// 2-stage software pipeline: 16 row-gathers in flight.
// ---------------------------------------------------------------------------
#define PG1(KK, S, G, WJ) do {                                                \
    const uint4 p = *(const uint4*)(sorted16 + (KK));                         \
    S[0] = p.x & 0xffffu; S[1] = p.x >> 16;                                   \
    S[2] = p.y & 0xffffu; S[3] = p.y >> 16;                                   \
    S[4] = p.z & 0xffffu; S[5] = p.z >> 16;                                   \
    S[6] = p.w & 0xffffu; S[7] = p.w >> 16;                                   \
    const u32 hlf = (head & 4) ? ((head & 2) ? p.w : p.z)                     \
                               : ((head & 2) ? p.y : p.x);                    \
    const u32 sj = (head & 1) ? (hlf >> 16) : (hlf & 0xffffu);                \
    WJ = __expf(LR(as1[sj * NH + eh] + adeh));                                \
    _Pragma("unroll") for (int j = 0; j < 8; ++j)                             \
        G[j] = h1b[S[j] * 64 + lane];                                         \
} while (0)

#define CONS1(G, WJ) do {                                                     \
    _Pragma("unroll") for (int j = 0; j < 8; ++j) {                           \
        const float wv = __uint_as_float((u32)__builtin_amdgcn_ds_bpermute(   \
            h4 + j * 32, (int)__float_as_uint(WJ)));                          \
        acc0 += wv * __uint_as_float(G[j] << 16);                             \
        acc1 += wv * __uint_as_float(G[j] & 0xffff0000u);                     \
        den  += wv; }                                                         \
} while (0)

__global__ __launch_bounds__(256) void k_agg1(
    const int* __restrict__ rowptr, const int* __restrict__ rowend,
    const u16* __restrict__ sorted16,
    const u32* __restrict__ h1b, const float* __restrict__ as1,
    const float* __restrict__ ad1,
    u32* __restrict__ act2b)
{
    const int node = blockIdx.x * 4 + (threadIdx.x >> 6);
    const int lane = threadIdx.x & 63;
    const int head = lane >> 3;          // accumulation head (channels 16h..)
    const int eh   = lane & 7;           // exp-role head
    const float adeh = ad1[node * NH + eh];
    const int k0 = rowptr[node], kend = rowend[node];   // kend-k0 multiple of 8, >=8
    const int h4 = head << 2;
    float acc0 = 0.f, acc1 = 0.f, den = 0.f;
    u32 sA[8], gA[8], sB[8], gB[8];
    float wA, wB;

    PG1(k0, sA, gA, wA);
    int k = k0 + 8;
    while (k + 16 <= kend) {
        PG1(k, sB, gB, wB);      CONS1(gA, wA);
        PG1(k + 8, sA, gA, wA);  CONS1(gB, wB);
        k += 16;
    }
    if (k < kend) {
        PG1(k, sB, gB, wB);  CONS1(gA, wA);  CONS1(gB, wB);
    } else {
        CONS1(gA, wA);
    }

    const float inv = 1.f / den;                    // self-loop => den > 0
    float v0 = acc0 * inv, v1 = acc1 * inv;
    v0 = v0 > 0.f ? v0 : expm1f(v0);                // ELU
    v1 = v1 > 0.f ? v1 : expm1f(v1);
    act2b[node * 64 + lane] = bf16rne(v0) | (bf16rne(v1) << 16);
}

// ---------------------------------------------------------------------------
// Aggregation layer 2 (fused edge weights) + log_softmax. Lane l computes the
// weight for edge (l&7) of the group (one exp instr / 8 edges); bpermute from
// lanes 0..7 broadcasts. Same uint4 packs + 2-stage pipeline.
// ---------------------------------------------------------------------------
#define PG2(KK, S, G, WJ) do {                                                \
    const uint4 p = *(const uint4*)(sorted16 + (KK));                         \
    S[0] = p.x & 0xffffu; S[1] = p.x >> 16;                                   \
    S[2] = p.y & 0xffffu; S[3] = p.y >> 16;                                   \
    S[4] = p.z & 0xffffu; S[5] = p.z >> 16;                                   \
    S[6] = p.w & 0xffffu; S[7] = p.w >> 16;                                   \
    const u32 hlf = (lane & 4) ? ((lane & 2) ? p.w : p.z)                     \
                               : ((lane & 2) ? p.y : p.x);                    \
    const u32 sj = (lane & 1) ? (hlf >> 16) : (hlf & 0xffffu);                \
    WJ = __expf(LR(as2[sj] + adv));                                           \
    _Pragma("unroll") for (int j = 0; j < 8; ++j)                             \
        G[j] = h2s[S[j] * 64 + lane];                                         \
} while (0)

#define CONS2(G, WJ) do {                                                     \
    _Pragma("unroll") for (int j = 0; j < 8; ++j) {                           \
        const float wv = __uint_as_float((u32)__builtin_amdgcn_ds_bpermute(   \
            j << 2, (int)__float_as_uint(WJ)));                               \
        acc += wv * __uint_as_float(((u32)G[j]) << 16);                       \
        den += wv; }                                                          \
} while (0)

__global__ __launch_bounds__(256) void k_agg2(
    const int* __restrict__ rowptr, const int* __restrict__ rowend,
    const u16* __restrict__ sorted16,
    const u16* __restrict__ h2s, const float* __restrict__ as2,
    const float* __restrict__ ad2,
    float* __restrict__ out)
{
    const int node = blockIdx.x * 4 + (threadIdx.x >> 6);
    const int lane = threadIdx.x & 63;
    const float adv = ad2[node];
    const int k0 = rowptr[node], kend = rowend[node];
    float acc = 0.f, den = 0.f;
    u32 sA[8], gA[8], sB[8], gB[8];
    float wA, wB;

    PG2(k0, sA, gA, wA);
    int k = k0 + 8;
    while (k + 16 <= kend) {
        PG2(k, sB, gB, wB);      CONS2(gA, wA);
        PG2(k + 8, sA, gA, wA);  CONS2(gB, wB);
        k += 16;
    }
    if (k < kend) {
        PG2(k, sB, gB, wB);  CONS2(gA, wA);  CONS2(gB, wB);
    } else {
        CONS2(gA, wA);
    }

    const float v = acc / den;
    float m = v;
    for (int kk = 1; kk < 64; kk <<= 1) m = fmaxf(m, __shfl_xor(m, kk));
    float se = __expf(v - m);
    for (int kk = 1; kk < 64; kk <<= 1) se += __shfl_xor(se, kk);
    out[node * 64 + lane] = v - m - logf(se);
}

// ---------------------------------------------------------------------------
// Workspace layout (u32 units, 64B-aligned chunks).
// ---------------------------------------------------------------------------
extern "C" void kernel_launch(void* const* d_in, const int* in_sizes, int n_in,
                              void* d_out, int out_size, void* d_ws, size_t ws_size,
                              hipStream_t stream)
{
    (void)in_sizes; (void)n_in; (void)out_size; (void)ws_size;
    const float* x    = (const float*)d_in[0];
    const int*   ei   = (const int*)d_in[1];
    const float* W1   = (const float*)d_in[2];
    const float* as1w = (const float*)d_in[3];
    const float* ad1w = (const float*)d_in[4];
    const float* W2   = (const float*)d_in[6];
    const float* as2w = (const float*)d_in[7];
    const float* ad2w = (const float*)d_in[8];
    float* out = (float*)d_out;

    u32* ws = (u32*)d_ws;
    size_t o = 0;
    auto take = [&](size_t n) { size_t r = o; o += (n + 15) & ~(size_t)15; return r; };

    u32*   h1b      = ws + take((size_t)64 * (NN + 1));
    float* as1      = (float*)(ws + take((size_t)NH * NN + 8));
    float* ad1      = (float*)(ws + take((size_t)NH * NN));
    u32*   act2b    = ws + take((size_t)64 * NN);
    float* as2      = (float*)(ws + take(NN + 1));
    float* ad2      = (float*)(ws + take(NN));
    int*   rowptr   = (int*)(ws + take(NN));
    int*   rowend   = (int*)(ws + take(NN));
    u16*   sorted16 = (u16*)(ws + take(((size_t)NB * BSTRIDE + 1) / 2));
    u32*   staging  = ws + take((size_t)NB * CAPB);
    int*   cnt      = (int*)(ws + take(NB * CPAD));
    u16*   Wt1      = (u16*)(ws + take((size_t)W1EXT * 128 / 2));
    u16*   Wt2      = (u16*)(ws + take((size_t)W2EXT * 128 / 2));
    u16*   h1s      = (u16*)h1b;
    u16*   h2s      = (u16*)h1b;          // alias (h1 dead after agg1)

    hipMemsetAsync(cnt, 0, NB * CPAD * sizeof(int), stream);

    k_prep_bin<<<NBB + WPB, 256, 0, stream>>>(
        ei, cnt, staging, W1, W2, as1w, ad1w, as2w, ad2w,
        Wt1, Wt2, h1b, as1, as2);

    k_place_gemm1<<<NB + G1B, 512, 0, stream>>>(
        cnt, staging, rowptr, rowend, sorted16, x, Wt1, h1s, as1, ad1);

    k_agg1<<<NN / 4, 256, 0, stream>>>(rowptr, rowend, sorted16, h1b, as1, ad1, act2b);
    k_gemm2<<<G1B, 512, 0, stream>>>(act2b, Wt2, h2s, as2, ad2);
    k_agg2<<<NN / 4, 256, 0, stream>>>(rowptr, rowend, sorted16, h2s, as2, ad2, out);
}